// Round 23
// baseline (890.655 us; speedup 1.0000x reference)
//
#include <hip/hip_runtime.h>

#define D_MODEL 256
#define HEADS 8
#define DH 32
#define DEPTH 2
#define DFF 2048
#define NO_HOPS 512
#define MAX_HOP_LEN 16
#define N_LEVELS 16
#define MAX_LEV_LEN 32
#define N_MASKED 512
#define N_NODES 8192
#define N_FINAL 2099   // 512 + 3*(512+16+1)
#define NLAY 26        // N_ENC * DEPTH
#define NSPLIT 8

typedef float f32x4 __attribute__((ext_vector_type(4)));
typedef short bf16x8 __attribute__((ext_vector_type(8)));
typedef short short4v __attribute__((ext_vector_type(4)));

#define GLOAD_LDS16(gp, lp) __builtin_amdgcn_global_load_lds( \
    (const __attribute__((address_space(1))) unsigned int*)(gp), \
    (__attribute__((address_space(3))) unsigned int*)(lp), 16, 0, 0)

__device__ __forceinline__ unsigned short f2bf(float f)
{
    unsigned int u = __builtin_bit_cast(unsigned int, f);
    unsigned int r = u + 0x7FFFu + ((u >> 16) & 1u);
    return (unsigned short)(r >> 16);
}

__device__ __forceinline__ float bf2f(unsigned short u)
{
    unsigned int x = (unsigned int)u << 16;
    return __builtin_bit_cast(float, x);
}

__device__ __forceinline__ bf16x8 cvt8(float4 a, float4 b)
{
    bf16x8 r;
    r[0] = (short)f2bf(a.x); r[1] = (short)f2bf(a.y);
    r[2] = (short)f2bf(a.z); r[3] = (short)f2bf(a.w);
    r[4] = (short)f2bf(b.x); r[5] = (short)f2bf(b.y);
    r[6] = (short)f2bf(b.z); r[7] = (short)f2bf(b.w);
    return r;
}

// ---------------- weight f32 -> bf16 conversion ----------------
__global__ void cvt_w(const float* __restrict__ src, unsigned short* __restrict__ dst, long n8)
{
    long i = (long)blockIdx.x * blockDim.x + threadIdx.x;
    if (i >= n8) return;
    const float4* s = reinterpret_cast<const float4*>(src) + i * 2;
    float4 a = s[0], b = s[1];
    *reinterpret_cast<bf16x8*>(dst + i * 8) = cvt8(a, b);
}

// ---------------- 64x128-tile GEMM: 48 KB LDS -> 3 blocks/CU ----------------------------
// rsA = element stride between consecutive A rows (rsA == K for dense; S*256 for CLS rows).
__global__ __launch_bounds__(256) void gemm_bb64(
    const unsigned short* __restrict__ A, const unsigned short* __restrict__ Wb,
    const float* __restrict__ bias, void* __restrict__ Yv,
    int M, int N, int K, int relu,
    unsigned long rsA, unsigned long xg, unsigned long wg, unsigned long bg, unsigned long yg)
{
    extern __shared__ unsigned short sh[];     // 24576 shorts = 48 KB
    const int grp = blockIdx.z;
    const int t = threadIdx.x;
    const int lane = t & 63, wid = t >> 6;
    const int wr = wid >> 1, wc = wid & 1;     // wave = 32 rows x 64 cols
    const int rowbase = blockIdx.y * 64;
    const int colbase = blockIdx.x * 128;
    const unsigned short* Abase = A + (size_t)grp * xg;
    const unsigned short* Wbase = Wb + (size_t)grp * wg;

    const unsigned short* gA[2]; unsigned short* lA[2];
    const unsigned short* gB[4]; unsigned short* lB[4];
    #pragma unroll
    for (int j = 0; j < 2; ++j) {
        int c = j * 256 + t;
        int sr = c >> 3, p = c & 7;
        int lc = p ^ (sr & 7);
        int ar = rowbase + sr; if (ar >= M) ar = M - 1;
        gA[j] = Abase + (size_t)ar * rsA + lc * 8;
        lA[j] = sh + (j * 256 + (t & ~63)) * 8;
    }
    #pragma unroll
    for (int j = 0; j < 4; ++j) {
        int c = j * 256 + t;
        int sr = c >> 3, p = c & 7;
        int lc = p ^ (sr & 7);
        gB[j] = Wbase + (size_t)(colbase + sr) * K + lc * 8;
        lB[j] = sh + 8192 + (j * 256 + (t & ~63)) * 8;
    }

    f32x4 acc[2][4];
    #pragma unroll
    for (int m = 0; m < 2; ++m)
        #pragma unroll
        for (int n = 0; n < 4; ++n)
            acc[m][n] = (f32x4){0.f, 0.f, 0.f, 0.f};

    const int g = lane >> 4, rr = lane & 15;
    const int nt = K >> 6;

    #pragma unroll
    for (int j = 0; j < 2; ++j) GLOAD_LDS16(gA[j], lA[j]);
    #pragma unroll
    for (int j = 0; j < 4; ++j) GLOAD_LDS16(gB[j], lB[j]);

    int buf = 0;
    for (int tt = 0; tt < nt; ++tt) {
        if (tt + 1 < nt) {
            const int k1 = (tt + 1) << 6;
            const int oa = (buf ^ 1) * 4096;
            const int ob = (buf ^ 1) * 8192;
            #pragma unroll
            for (int j = 0; j < 2; ++j) GLOAD_LDS16(gA[j] + k1, lA[j] + oa);
            #pragma unroll
            for (int j = 0; j < 4; ++j) GLOAD_LDS16(gB[j] + k1, lB[j] + ob);
            asm volatile("s_waitcnt vmcnt(6)\n\ts_barrier" ::: "memory");
        } else {
            asm volatile("s_waitcnt vmcnt(0)\n\ts_barrier" ::: "memory");
        }
        const unsigned short* Ab = sh + buf * 4096;
        const unsigned short* Bb = sh + 8192 + buf * 8192;
        #pragma unroll
        for (int ks = 0; ks < 2; ++ks) {
            bf16x8 af[2], bfr[4];
            #pragma unroll
            for (int m = 0; m < 2; ++m) {
                int row = wr * 32 + m * 16 + rr;
                int lc = ks * 4 + g;
                af[m] = *reinterpret_cast<const bf16x8*>(&Ab[row * 64 + ((lc ^ (row & 7)) * 8)]);
            }
            #pragma unroll
            for (int n = 0; n < 4; ++n) {
                int col = wc * 64 + n * 16 + rr;
                int lc = ks * 4 + g;
                bfr[n] = *reinterpret_cast<const bf16x8*>(&Bb[col * 64 + ((lc ^ (col & 7)) * 8)]);
            }
            #pragma unroll
            for (int m = 0; m < 2; ++m)
                #pragma unroll
                for (int n = 0; n < 4; ++n)
                    acc[m][n] = __builtin_amdgcn_mfma_f32_16x16x32_bf16(af[m], bfr[n], acc[m][n], 0, 0, 0);
        }
        asm volatile("s_barrier" ::: "memory");
        buf ^= 1;
    }

    const int rg = lane >> 4;
    const float* bp = bias + (size_t)grp * bg;
    #pragma unroll
    for (int n = 0; n < 4; ++n) {
        int coll = wc * 64 + n * 16 + rr;
        float bv = bp[colbase + coll];
        #pragma unroll
        for (int m = 0; m < 2; ++m) {
            #pragma unroll
            for (int i = 0; i < 4; ++i) {
                int rowl = wr * 32 + m * 16 + rg * 4 + i;
                float v = acc[m][n][i] + bv;
                if (relu) v = fmaxf(v, 0.f);
                sh[rowl * 128 + coll] = f2bf(v);
            }
        }
    }
    __syncthreads();
    unsigned short* Y = (unsigned short*)Yv + (size_t)grp * yg;
    int row = t >> 2, seg = t & 3;
    int grow = rowbase + row;
    if (grow < M) {
        const unsigned short* s = &sh[row * 128 + seg * 32];
        unsigned short* d = Y + (size_t)grow * N + colbase + seg * 32;
        #pragma unroll
        for (int j = 0; j < 4; ++j)
            *reinterpret_cast<bf16x8*>(d + j * 8) = *reinterpret_cast<const bf16x8*>(s + j * 8);
    }
}

// ---------------- fused N=256 GEMM + residual + LayerNorm --------------------------------
// Block owns 64 FULL rows (256 cols): no inter-block sharing of any written data.
// Y[row] = LN( bf16(A[row]*W^T + bias) + R[row] ).  BK=32, LDS 41984 B -> 3 blocks/CU.
// A rows strided rsA; residual rows strided rsR; output rows dense (256).
__global__ __launch_bounds__(256) void gemm_n256_ln(
    const unsigned short* __restrict__ A, const unsigned short* __restrict__ R,
    const unsigned short* __restrict__ Wb, const float* __restrict__ bias,
    const float* __restrict__ lnw, const float* __restrict__ lnb,
    unsigned short* __restrict__ Y,
    int M, int K,
    unsigned long rsA, unsigned long rsR,
    unsigned long xg, unsigned long rg_, unsigned long wg, unsigned long bg,
    unsigned long lg, unsigned long yg)
{
    extern __shared__ unsigned short sh[];   // A dbuf @0 (2x2048), B dbuf @4096 (2x8192); out @4096 [64][264]
    const int grp = blockIdx.z;
    const int t = threadIdx.x;
    const int lane = t & 63, wid = t >> 6;
    const int rowbase = blockIdx.x * 64;
    const unsigned short* Abase = A + (size_t)grp * xg;
    const unsigned short* Rg = R + (size_t)grp * rg_;
    const unsigned short* Wbase = Wb + (size_t)grp * wg;

    // A staging: 64 rows x 32 k = 2048 shorts, 1 chunk (16B) per thread
    const unsigned short* gA; unsigned short* lA;
    {
        int sr = t >> 2, p = t & 3;
        int lc = p ^ (sr & 3);
        int ar = rowbase + sr; if (ar >= M) ar = M - 1;
        gA = Abase + (size_t)ar * rsA + lc * 8;
        lA = sh + (t & ~63) * 8;
    }
    // B staging: 256 cols x 32 k = 8192 shorts, 4 chunks per thread
    const unsigned short* gB[4]; unsigned short* lB[4];
    #pragma unroll
    for (int j = 0; j < 4; ++j) {
        int c = j * 256 + t;
        int sr = c >> 2, p = c & 3;
        int lc = p ^ (sr & 3);
        gB[j] = Wbase + (size_t)sr * K + lc * 8;
        lB[j] = sh + 4096 + (j * 256 + (t & ~63)) * 8;
    }

    f32x4 acc[4][4];
    #pragma unroll
    for (int m = 0; m < 4; ++m)
        #pragma unroll
        for (int n = 0; n < 4; ++n)
            acc[m][n] = (f32x4){0.f, 0.f, 0.f, 0.f};

    const int g = lane >> 4, rr = lane & 15;
    const int nt = K >> 5;

    GLOAD_LDS16(gA, lA);
    #pragma unroll
    for (int j = 0; j < 4; ++j) GLOAD_LDS16(gB[j], lB[j]);

    int buf = 0;
    for (int tt = 0; tt < nt; ++tt) {
        if (tt + 1 < nt) {
            const int k1 = (tt + 1) << 5;
            GLOAD_LDS16(gA + k1, lA + (buf ^ 1) * 2048);
            #pragma unroll
            for (int j = 0; j < 4; ++j) GLOAD_LDS16(gB[j] + k1, lB[j] + (buf ^ 1) * 8192);
            asm volatile("s_waitcnt vmcnt(5)\n\ts_barrier" ::: "memory");
        } else {
            asm volatile("s_waitcnt vmcnt(0)\n\ts_barrier" ::: "memory");
        }
        const unsigned short* Ab = sh + buf * 2048;
        const unsigned short* Bb = sh + 4096 + buf * 8192;
        bf16x8 af[4], bfr[4];
        #pragma unroll
        for (int m = 0; m < 4; ++m) {
            int row = m * 16 + rr;
            af[m] = *reinterpret_cast<const bf16x8*>(&Ab[row * 32 + ((g ^ (row & 3)) * 8)]);
        }
        #pragma unroll
        for (int n = 0; n < 4; ++n) {
            int col = wid * 64 + n * 16 + rr;
            bfr[n] = *reinterpret_cast<const bf16x8*>(&Bb[col * 32 + ((g ^ (col & 3)) * 8)]);
        }
        #pragma unroll
        for (int m = 0; m < 4; ++m)
            #pragma unroll
            for (int n = 0; n < 4; ++n)
                acc[m][n] = __builtin_amdgcn_mfma_f32_16x16x32_bf16(af[m], bfr[n], acc[m][n], 0, 0, 0);
        asm volatile("s_barrier" ::: "memory");
        buf ^= 1;
    }

    // epilogue: bf16(acc + bias) into padded [64][264] LDS tile (reuses B area; A area untouched)
    const int PD = 264;
    unsigned short* shOut = sh + 4096;
    const float* bp = bias + (size_t)grp * bg;
    #pragma unroll
    for (int n = 0; n < 4; ++n) {
        int coll = wid * 64 + n * 16 + rr;
        float bv = bp[coll];
        #pragma unroll
        for (int m = 0; m < 4; ++m) {
            #pragma unroll
            for (int i = 0; i < 4; ++i) {
                int rowl = m * 16 + g * 4 + i;
                shOut[rowl * PD + coll] = f2bf(acc[m][n][i] + bv);
            }
        }
    }
    __syncthreads();

    // LN over full rows: 4 threads per row, 64 elems each; bit-pattern matches add_ln path
    {
        int row = t >> 2, seg = t & 3;
        int grow = rowbase + row;
        int valid = grow < M;
        int gr = valid ? grow : M - 1;
        const unsigned short* rp = Rg + (size_t)gr * rsR + seg * 64;
        const unsigned short* xp = &shOut[row * PD + seg * 64];
        float sum = 0.f;
        #pragma unroll
        for (int j = 0; j < 8; ++j) {
            bf16x8 xv = *reinterpret_cast<const bf16x8*>(xp + j * 8);
            bf16x8 rv = *reinterpret_cast<const bf16x8*>(rp + j * 8);
            #pragma unroll
            for (int k = 0; k < 8; ++k)
                sum += bf2f((unsigned short)xv[k]) + bf2f((unsigned short)rv[k]);
        }
        sum += __shfl_xor(sum, 1, 64);
        sum += __shfl_xor(sum, 2, 64);
        float mu = sum * (1.f / D_MODEL);
        float sq = 0.f;
        #pragma unroll
        for (int j = 0; j < 8; ++j) {
            bf16x8 xv = *reinterpret_cast<const bf16x8*>(xp + j * 8);
            bf16x8 rv = *reinterpret_cast<const bf16x8*>(rp + j * 8);
            #pragma unroll
            for (int k = 0; k < 8; ++k) {
                float v = bf2f((unsigned short)xv[k]) + bf2f((unsigned short)rv[k]);
                float d = v - mu;
                sq += d * d;
            }
        }
        sq += __shfl_xor(sq, 1, 64);
        sq += __shfl_xor(sq, 2, 64);
        float inv = rsqrtf(sq * (1.f / D_MODEL) + 1e-5f);
        const float* wlp = lnw + (size_t)grp * lg + seg * 64;
        const float* blp = lnb + (size_t)grp * lg + seg * 64;
        unsigned short* yo = Y + (size_t)grp * yg + (size_t)gr * D_MODEL + seg * 64;
        if (valid) {
            #pragma unroll
            for (int j = 0; j < 8; ++j) {
                bf16x8 xv = *reinterpret_cast<const bf16x8*>(xp + j * 8);
                bf16x8 rv = *reinterpret_cast<const bf16x8*>(rp + j * 8);
                bf16x8 ov;
                #pragma unroll
                for (int k = 0; k < 8; ++k) {
                    float v = bf2f((unsigned short)xv[k]) + bf2f((unsigned short)rv[k]);
                    float out = (v - mu) * inv * wlp[j * 8 + k] + blp[j * 8 + k];
                    ov[k] = (short)f2bf(out);
                }
                *reinterpret_cast<bf16x8*>(yo + j * 8) = ov;
            }
        }
    }
}

// ---------------- small-S attention (S <= 32): one wave per (b,h), 4 per block ----------
__global__ __launch_bounds__(256) void attn_small(
    const unsigned short* __restrict__ QKV, const int* __restrict__ lengths,
    unsigned short* __restrict__ O, int B, int S)
{
    __shared__ __align__(16) unsigned short Ksm[4][32][40];
    __shared__ __align__(16) unsigned short Vsm[4][32][40];
    __shared__ __align__(16) unsigned short Psm[4][32][40];
    const int t = threadIdx.x;
    const int w = t >> 6, lane = t & 63;
    const int l15 = lane & 15, g = lane >> 4;
    int bh = blockIdx.x * 4 + w;
    const int BH = B * HEADS;
    if (bh >= BH) bh = BH - 1;
    const int b = bh >> 3, h = bh & 7;
    const unsigned short* base = QKV + (size_t)b * S * (3 * D_MODEL);
    int len_eff = S - 1;
    if (lengths) { int L = lengths[b]; if (L < len_eff) len_eff = L; }

    {
        int key = lane >> 1, hf = lane & 1;
        int kg = key < S ? key : S - 1;
        const unsigned short* kp = base + (size_t)kg * (3 * D_MODEL) + D_MODEL + h * DH + hf * 16;
        bf16x8 k0 = *reinterpret_cast<const bf16x8*>(kp);
        bf16x8 k1 = *reinterpret_cast<const bf16x8*>(kp + 8);
        *reinterpret_cast<bf16x8*>(&Ksm[w][key][hf * 16]) = k0;
        *reinterpret_cast<bf16x8*>(&Ksm[w][key][hf * 16 + 8]) = k1;
        const unsigned short* vp = kp + D_MODEL;
        bf16x8 v0 = *reinterpret_cast<const bf16x8*>(vp);
        bf16x8 v1 = *reinterpret_cast<const bf16x8*>(vp + 8);
        #pragma unroll
        for (int i = 0; i < 8; ++i) {
            Vsm[w][hf * 16 + i][key]     = (unsigned short)v0[i];
            Vsm[w][hf * 16 + 8 + i][key] = (unsigned short)v1[i];
        }
    }
    bf16x8 qa[2];
    #pragma unroll
    for (int qf = 0; qf < 2; ++qf) {
        int q = qf * 16 + l15; if (q > S - 1) q = S - 1;
        qa[qf] = *reinterpret_cast<const bf16x8*>(base + (size_t)q * (3 * D_MODEL) + h * DH + g * 8);
    }
    __syncthreads();

    const float scale = 0.17677669529663687f;
    const f32x4 zero = (f32x4){0.f,0.f,0.f,0.f};
    f32x4 sc[2][2];
    #pragma unroll
    for (int kf = 0; kf < 2; ++kf) {
        bf16x8 kb = *reinterpret_cast<const bf16x8*>(&Ksm[w][kf * 16 + l15][g * 8]);
        #pragma unroll
        for (int qf = 0; qf < 2; ++qf)
            sc[qf][kf] = __builtin_amdgcn_mfma_f32_16x16x32_bf16(qa[qf], kb, zero, 0, 0, 0);
    }
    float rsum[2][4];
    #pragma unroll
    for (int qf = 0; qf < 2; ++qf) {
        #pragma unroll
        for (int kf = 0; kf < 2; ++kf) {
            if (kf * 16 + l15 > len_eff) sc[qf][kf] = (f32x4){-1e9f,-1e9f,-1e9f,-1e9f};
            else sc[qf][kf] *= scale;
        }
        #pragma unroll
        for (int r = 0; r < 4; ++r) {
            float mx = fmaxf(sc[qf][0][r], sc[qf][1][r]);
            mx = fmaxf(mx, __shfl_xor(mx, 1, 64));
            mx = fmaxf(mx, __shfl_xor(mx, 2, 64));
            mx = fmaxf(mx, __shfl_xor(mx, 4, 64));
            mx = fmaxf(mx, __shfl_xor(mx, 8, 64));
            float s0 = __expf(sc[qf][0][r] - mx);
            float s1 = __expf(sc[qf][1][r] - mx);
            sc[qf][0][r] = s0;
            sc[qf][1][r] = s1;
            float ss = s0 + s1;
            ss += __shfl_xor(ss, 1, 64);
            ss += __shfl_xor(ss, 2, 64);
            ss += __shfl_xor(ss, 4, 64);
            ss += __shfl_xor(ss, 8, 64);
            rsum[qf][r] = ss;
        }
    }
    #pragma unroll
    for (int qf = 0; qf < 2; ++qf)
        #pragma unroll
        for (int kf = 0; kf < 2; ++kf)
            #pragma unroll
            for (int r = 0; r < 4; ++r)
                Psm[w][qf * 16 + g * 4 + r][kf * 16 + l15] = f2bf(sc[qf][kf][r]);
    __syncthreads();

    f32x4 o[2][2];
    #pragma unroll
    for (int df = 0; df < 2; ++df) {
        bf16x8 vb = *reinterpret_cast<const bf16x8*>(&Vsm[w][df * 16 + l15][g * 8]);
        #pragma unroll
        for (int qf = 0; qf < 2; ++qf) {
            bf16x8 pa = *reinterpret_cast<const bf16x8*>(&Psm[w][qf * 16 + l15][g * 8]);
            o[qf][df] = __builtin_amdgcn_mfma_f32_16x16x32_bf16(pa, vb, zero, 0, 0, 0);
        }
    }
    #pragma unroll
    for (int qf = 0; qf < 2; ++qf)
        #pragma unroll
        for (int r = 0; r < 4; ++r) {
            int q = qf * 16 + g * 4 + r;
            if (q < S) {
                float inv = 1.f / rsum[qf][r];
                #pragma unroll
                for (int df = 0; df < 2; ++df)
                    O[((size_t)b * S + q) * D_MODEL + h * DH + df * 16 + l15] = f2bf(o[qf][df][r] * inv);
            }
        }
}

// ---------------- MFMA flash attention; SPLIT=1: K-split partials (B must be 1) ----------
template<int SPLIT>
__global__ __launch_bounds__(256) void attn_flash(
    const unsigned short* __restrict__ QKV, const int* __restrict__ lengths,
    unsigned short* __restrict__ O, int B, int S,
    int NSv, float* __restrict__ pAcc, float* __restrict__ pMS)
{
    __shared__ __align__(16) unsigned short Kt[64][32];
    __shared__ __align__(16) unsigned short Vt[32][64];
    __shared__ __align__(16) unsigned short Pw[4][16][64];

    const int t = threadIdx.x;
    const int lane = t & 63, wid = t >> 6;
    const int l15 = lane & 15, g = lane >> 4;
    const int b = SPLIT ? 0 : blockIdx.z;
    const int sp = SPLIT ? blockIdx.z : 0;
    const int h = blockIdx.y;
    const int qb = blockIdx.x * 64 + wid * 16;
    const unsigned short* base = QKV + (size_t)b * S * (3 * D_MODEL);

    int len_eff = S - 1;
    if (lengths) { int L = lengths[b]; if (L < len_eff) len_eff = L; }

    const float scale = 0.17677669529663687f;
    int qrow = qb + l15; if (qrow > S - 1) qrow = S - 1;
    bf16x8 qa = *reinterpret_cast<const bf16x8*>(base + (size_t)qrow * (3 * D_MODEL) + h * DH + g * 8);

    float m[4], sum[4];
    f32x4 o[2];
    #pragma unroll
    for (int r = 0; r < 4; ++r) { m[r] = -3.0e38f; sum[r] = 0.f; }
    o[0] = (f32x4){0.f,0.f,0.f,0.f};
    o[1] = (f32x4){0.f,0.f,0.f,0.f};

    const int kl = t >> 2, cg = t & 3;
    const int ntiles_all = (S + 63) >> 6;
    int tstart = 0, tend = ntiles_all;
    if (SPLIT) {
        int chunkT = (ntiles_all + NSv - 1) / NSv;
        tstart = sp * chunkT;
        tend = tstart + chunkT;
        if (tend > ntiles_all) tend = ntiles_all;
    }

    for (int tt = tstart; tt < tend; ++tt) {
        const int kbase = tt * 64;
        {
            int key = kbase + kl; if (key > S - 1) key = S - 1;
            const unsigned short* kp = base + (size_t)key * (3 * D_MODEL) + D_MODEL + h * DH + cg * 8;
            *reinterpret_cast<bf16x8*>(&Kt[kl][cg * 8]) = *reinterpret_cast<const bf16x8*>(kp);
            bf16x8 vv = *reinterpret_cast<const bf16x8*>(kp + D_MODEL);
            #pragma unroll
            for (int i = 0; i < 8; ++i) {
                int d = cg * 8 + i;
                int c = ((kl >> 3) ^ (d & 7)) * 8 + (kl & 7);
                Vt[d][c] = (unsigned short)vv[i];
            }
        }
        __syncthreads();

        f32x4 sc[4];
        const f32x4 zero = (f32x4){0.f,0.f,0.f,0.f};
        #pragma unroll
        for (int f = 0; f < 4; ++f) {
            bf16x8 kf = *reinterpret_cast<const bf16x8*>(&Kt[f * 16 + l15][g * 8]);
            sc[f] = __builtin_amdgcn_mfma_f32_16x16x32_bf16(qa, kf, zero, 0, 0, 0);
            sc[f] *= scale;
        }
        #pragma unroll
        for (int f = 0; f < 4; ++f) {
            if (kbase + f * 16 + l15 > len_eff)
                sc[f] = (f32x4){-1e9f,-1e9f,-1e9f,-1e9f};
        }
        float cr[4];
        #pragma unroll
        for (int r = 0; r < 4; ++r) {
            float mx = fmaxf(fmaxf(sc[0][r], sc[1][r]), fmaxf(sc[2][r], sc[3][r]));
            mx = fmaxf(mx, __shfl_xor(mx, 1, 64));
            mx = fmaxf(mx, __shfl_xor(mx, 2, 64));
            mx = fmaxf(mx, __shfl_xor(mx, 4, 64));
            mx = fmaxf(mx, __shfl_xor(mx, 8, 64));
            float nm = fmaxf(m[r], mx);
            cr[r] = __expf(m[r] - nm);
            m[r] = nm;
            float ssum = 0.f;
            #pragma unroll
            for (int f = 0; f < 4; ++f) {
                float e = __expf(sc[f][r] - nm);
                sc[f][r] = e;
                ssum += e;
            }
            ssum += __shfl_xor(ssum, 1, 64);
            ssum += __shfl_xor(ssum, 2, 64);
            ssum += __shfl_xor(ssum, 4, 64);
            ssum += __shfl_xor(ssum, 8, 64);
            sum[r] = sum[r] * cr[r] + ssum;
            o[0][r] *= cr[r];
            o[1][r] *= cr[r];
        }
        #pragma unroll
        for (int f = 0; f < 4; ++f) {
            int chunk = f * 2 + (l15 >> 3);
            #pragma unroll
            for (int r = 0; r < 4; ++r) {
                int row = g * 4 + r;
                Pw[wid][row][(chunk ^ (row & 7)) * 8 + (l15 & 7)] = f2bf(sc[f][r]);
            }
        }
        #pragma unroll
        for (int s = 0; s < 2; ++s) {
            bf16x8 pa = *reinterpret_cast<const bf16x8*>(
                &Pw[wid][l15][((s * 4 + g) ^ (l15 & 7)) * 8]);
            #pragma unroll
            for (int jf = 0; jf < 2; ++jf) {
                int d = jf * 16 + l15;
                bf16x8 vb = *reinterpret_cast<const bf16x8*>(
                    &Vt[d][((s * 4 + g) ^ (d & 7)) * 8]);
                o[jf] = __builtin_amdgcn_mfma_f32_16x16x32_bf16(pa, vb, o[jf], 0, 0, 0);
            }
        }
        __syncthreads();
    }

    if (SPLIT) {
        #pragma unroll
        for (int r = 0; r < 4; ++r) {
            int qout = qb + g * 4 + r;
            if (qout < S) {
                size_t pb = ((size_t)qout * HEADS + h) * NSv + sp;
                pAcc[pb * 32 + l15]      = o[0][r];
                pAcc[pb * 32 + 16 + l15] = o[1][r];
                if (l15 == 0) { pMS[pb * 2] = m[r]; pMS[pb * 2 + 1] = sum[r]; }
            }
        }
    } else {
        #pragma unroll
        for (int r = 0; r < 4; ++r) {
            float inv = 1.f / sum[r];
            int qout = qb + g * 4 + r;
            if (qout < S) {
                #pragma unroll
                for (int jf = 0; jf < 2; ++jf)
                    O[((size_t)b * S + qout) * D_MODEL + h * DH + jf * 16 + l15] = f2bf(o[jf][r] * inv);
            }
        }
    }
}

// ---------------- split-K merge ----------------
__global__ void attn_merge(const float* __restrict__ pAcc, const float* __restrict__ pMS,
                           unsigned short* __restrict__ O, int S, int NS)
{
    int idx = blockIdx.x * blockDim.x + threadIdx.x;
    if (idx >= S * HEADS * DH) return;
    int d = idx & 31;
    int h = (idx >> 5) & 7;
    int q = idx >> 8;
    size_t base = ((size_t)q * HEADS + h) * NS;
    float mstar = -3.0e38f;
    for (int s = 0; s < NS; ++s) mstar = fmaxf(mstar, pMS[(base + s) * 2]);
    float ssum = 0.f, acc = 0.f;
    for (int s = 0; s < NS; ++s) {
        float mi = pMS[(base + s) * 2];
        float si = pMS[(base + s) * 2 + 1];
        float w = __expf(mi - mstar);
        ssum += si * w;
        acc += pAcc[(base + s) * 32 + d] * w;
    }
    O[(size_t)q * D_MODEL + h * DH + d] = f2bf(acc / ssum);
}

// ---------------- builders (bf16 Xb only) ----------------
__global__ void build_hop_seq_g(const float* __restrict__ tok, const int* __restrict__ hlist,
                                const float* __restrict__ hop_nodes,
                                unsigned short* __restrict__ Xb, int nm)
{
    int idx = blockIdx.x * blockDim.x + threadIdx.x;
    const int per = NO_HOPS * (MAX_HOP_LEN + 1) * D_MODEL;
    if (idx >= nm * per) return;
    int g = idx / per, r = idx % per;
    int d = r & 255;
    int rest = r >> 8;
    int p = rest % (MAX_HOP_LEN + 1);
    int hh = rest / (MAX_HOP_LEN + 1);
    float v;
    if (p == 0) v = hop_nodes[d];
    else {
        int node = hlist[(size_t)g * NO_HOPS * MAX_HOP_LEN + hh * MAX_HOP_LEN + p - 1];
        v = tok[(size_t)g * N_NODES * D_MODEL + (size_t)node * D_MODEL + d];
    }
    Xb[idx] = f2bf(v);
}

__global__ void compute_pos_g(const int* __restrict__ hop_lev, int* __restrict__ pos,
                              int* __restrict__ counts)
{
    int g = blockIdx.x;
    const int* lev = hop_lev + (size_t)g * NO_HOPS;
    int i = threadIdx.x;
    int li = lev[i];
    int p = 0;
    for (int j = 0; j < i; ++j) p += (lev[j] == li);
    pos[(size_t)g * NO_HOPS + i] = p;
    if (i < N_LEVELS) {
        int c = 0;
        for (int j = 0; j < NO_HOPS; ++j) c += (lev[j] == i);
        counts[(size_t)g * N_LEVELS + i] = c;
    }
}

__global__ void build_level_init_g(const float* __restrict__ level_nodes,
                                   unsigned short* __restrict__ Gb, int nm)
{
    int idx = blockIdx.x * blockDim.x + threadIdx.x;
    const int per = N_LEVELS * (MAX_LEV_LEN + 1) * D_MODEL;
    if (idx >= nm * per) return;
    int r = idx % per;
    int d = r & 255;
    int p = (r >> 8) % (MAX_LEV_LEN + 1);
    float v = (p == 0) ? level_nodes[d] : 0.f;
    Gb[idx] = f2bf(v);
}

__global__ void scatter_hops_g(const float* __restrict__ hop_tok, const int* __restrict__ hop_lev,
                               const int* __restrict__ pos,
                               unsigned short* __restrict__ Gb, int nm)
{
    int idx = blockIdx.x * blockDim.x + threadIdx.x;
    const int per = NO_HOPS * D_MODEL;
    if (idx >= nm * per) return;
    int g = idx / per, r = idx % per;
    int d = r & 255;
    int i = r >> 8;
    int lv = hop_lev[(size_t)g * NO_HOPS + i];
    int ps = pos[(size_t)g * NO_HOPS + i];
    size_t dst = (size_t)g * N_LEVELS * (MAX_LEV_LEN + 1) * D_MODEL +
                 ((size_t)lv * (MAX_LEV_LEN + 1) + 1 + ps) * D_MODEL + d;
    Gb[dst] = f2bf(hop_tok[idx]);
}

__global__ void build_graph_seq_g(const float* __restrict__ graph_nodes,
                                  const float* __restrict__ lev_tok,
                                  unsigned short* __restrict__ Xb, int nm)
{
    int idx = blockIdx.x * blockDim.x + threadIdx.x;
    const int per = (N_LEVELS + 1) * D_MODEL;
    if (idx >= nm * per) return;
    int g = idx / per, r = idx % per;
    int d = r & 255;
    int p = r >> 8;
    float v = (p == 0) ? graph_nodes[d]
                       : lev_tok[(size_t)g * N_LEVELS * D_MODEL + (size_t)(p - 1) * D_MODEL + d];
    Xb[idx] = f2bf(v);
}

__global__ void build_final_seq(const float* __restrict__ masked, const float* __restrict__ hoptok,
                                const float* __restrict__ levtok, const float* __restrict__ gtok,
                                unsigned short* __restrict__ Xb)
{
    int idx = blockIdx.x * blockDim.x + threadIdx.x;
    const int total = N_FINAL * D_MODEL;
    if (idx >= total) return;
    int d = idx & 255;
    int r = idx >> 8;
    float v;
    if (r < N_MASKED) v = masked[idx];
    else {
        int t = r - N_MASKED;
        int m = t / 529;
        int w = t % 529;
        if (w < 512)      v = hoptok[((size_t)m * 512 + w) * D_MODEL + d];
        else if (w < 528) v = levtok[((size_t)m * 16 + (w - 512)) * D_MODEL + d];
        else              v = gtok[m * D_MODEL + d];
    }
    Xb[idx] = f2bf(v);
}

__global__ void extract_cls(const unsigned short* __restrict__ Xb, float* __restrict__ out,
                            int B, int S)
{
    int idx = blockIdx.x * blockDim.x + threadIdx.x;
    if (idx >= B * D_MODEL) return;
    int b = idx >> 8;
    int d = idx & 255;
    out[idx] = bf2f(Xb[(size_t)b * S * D_MODEL + d]);
}

__global__ void copy_out_kernel(const unsigned short* __restrict__ src, float* __restrict__ dst, int n)
{
    int i = blockIdx.x * blockDim.x + threadIdx.x;
    if (i < n) dst[i] = bf2f(src[i]);
}

// ---------------- host orchestration ----------------
struct WB {
    const unsigned short *inw, *outw, *f1w, *f2w;
    const float *in_b, *out_b, *ff1_b, *ff2_b, *ln1_w, *ln1_b, *ln2_w, *ln2_b;
};

#define SZ_INW  ((size_t)3 * D_MODEL * D_MODEL)
#define SZ_OUTW ((size_t)D_MODEL * D_MODEL)
#define SZ_F1W  ((size_t)DFF * D_MODEL)
#define SZ_F2W  ((size_t)D_MODEL * DFF)
#define GS_INW  ((unsigned long)DEPTH * SZ_INW)
#define GS_INB  ((unsigned long)DEPTH * 3 * D_MODEL)
#define GS_OUTW ((unsigned long)DEPTH * SZ_OUTW)
#define GS_OUTB ((unsigned long)DEPTH * D_MODEL)
#define GS_F1W  ((unsigned long)DEPTH * SZ_F1W)
#define GS_F1B  ((unsigned long)DEPTH * DFF)
#define GS_F2W  ((unsigned long)DEPTH * SZ_F2W)
#define GS_F2B  ((unsigned long)DEPTH * D_MODEL)
#define GS_LN   ((unsigned long)DEPTH * D_MODEL)

static void launch_gemm(const unsigned short* A, unsigned long rsA, const unsigned short* Wb,
                        const float* bias, void* Yv, int M, int N, int K, int relu, int nm,
                        unsigned long xg, unsigned long wg, unsigned long bg, unsigned long yg,
                        hipStream_t stream)
{
    dim3 grid(N / 128, (M + 63) / 64, nm);
    hipLaunchKernelGGL(gemm_bb64, grid, dim3(256), 49152, stream,
                       A, Wb, bias, Yv, M, N, K, relu, rsA, xg, wg, bg, yg);
}

static void launch_gemm_ln(const unsigned short* A, unsigned long rsA, unsigned long xg,
                           const unsigned short* R, unsigned long rsR, unsigned long rg,
                           const unsigned short* Wb, unsigned long wg,
                           const float* bias, unsigned long bg,
                           const float* lnw, const float* lnb, unsigned long lg,
                           unsigned short* Y, unsigned long yg,
                           int M, int K, int nm, hipStream_t stream)
{
    dim3 grid((M + 63) / 64, 1, nm);
    hipLaunchKernelGGL(gemm_n256_ln, grid, dim3(256), 41984, stream,
                       A, R, Wb, bias, lnw, lnb, Y, M, K,
                       rsA, rsR, xg, rg, wg, bg, lg, yg);
}

static void run_layer_g(unsigned short* Xb, unsigned short* QKV, unsigned short* O,
                        unsigned short* Tb, unsigned short* FF,
                        unsigned short* XC1, unsigned short* TC, unsigned short* XC2,
                        float* skAcc, float* skMS,
                        int ff_rows, int nm, int Btot, int S,
                        const int* lengths, const WB& W, int eid0, int l, int last,
                        hipStream_t stream)
{
    (void)Tb; (void)TC;
    const int Bpg = Btot / nm;
    const int Mpg = Bpg * S;
    const size_t il = (size_t)eid0 * DEPTH + l;
    // QKV: always full (K/V needed for all positions)
    launch_gemm(Xb, D_MODEL, W.inw + il * SZ_INW, W.in_b + il * 3 * D_MODEL, QKV,
                Mpg, 3 * D_MODEL, D_MODEL, 0, nm,
                (unsigned long)Mpg * D_MODEL, GS_INW, GS_INB, (unsigned long)Mpg * 3 * D_MODEL,
                stream);
    {
        int qspan = S;
        if (last && Btot == 1 && S >= 1024) qspan = N_MASKED;  // final encoder: only first 512 q rows
        int qtiles = (qspan + 63) / 64;
        if (S <= 32) {
            int blocks = (Btot * HEADS + 3) / 4;
            hipLaunchKernelGGL(attn_small, dim3(blocks), dim3(256), 0, stream,
                               QKV, lengths, O, Btot, S);
        } else if (Btot == 1 && S >= 1024) {
            dim3 grid(qtiles, HEADS, NSPLIT);
            hipLaunchKernelGGL((attn_flash<1>), grid, dim3(256), 0, stream,
                               QKV, lengths, O, Btot, S, NSPLIT, skAcc, skMS);
            int tot = qspan * HEADS * DH;
            hipLaunchKernelGGL(attn_merge, dim3((tot + 255) / 256), dim3(256), 0, stream,
                               skAcc, skMS, O, qspan, NSPLIT);
        } else {
            dim3 grid(qtiles, HEADS, Btot);
            hipLaunchKernelGGL((attn_flash<0>), grid, dim3(256), 0, stream,
                               QKV, lengths, O, Btot, S, 1, (float*)nullptr, (float*)nullptr);
        }
    }
    if (!last) {
        // fused out-proj + residual(Xb) + LN1 -> Xb  (row-exclusive per block, in-place safe)
        launch_gemm_ln(O, D_MODEL, (unsigned long)Mpg * D_MODEL,
                       Xb, D_MODEL, (unsigned long)Mpg * D_MODEL,
                       W.outw + il * SZ_OUTW, GS_OUTW,
                       W.out_b + il * D_MODEL, GS_OUTB,
                       W.ln1_w + il * D_MODEL, W.ln1_b + il * D_MODEL, GS_LN,
                       Xb, (unsigned long)Mpg * D_MODEL,
                       Mpg, D_MODEL, nm, stream);
        for (int m0 = 0; m0 < Mpg; m0 += ff_rows) {
            int mc = (Mpg - m0 < ff_rows) ? (Mpg - m0) : ff_rows;
            launch_gemm(Xb + (size_t)m0 * D_MODEL, D_MODEL,
                        W.f1w + il * SZ_F1W, W.ff1_b + il * DFF, FF,
                        mc, DFF, D_MODEL, 1, nm,
                        (unsigned long)Mpg * D_MODEL, GS_F1W, GS_F1B, (unsigned long)mc * DFF,
                        stream);
            // fused FF2 + residual(Xb rows) + LN2 -> Xb
            launch_gemm_ln(FF, DFF, (unsigned long)mc * DFF,
                           Xb + (size_t)m0 * D_MODEL, D_MODEL, (unsigned long)Mpg * D_MODEL,
                           W.f2w + il * SZ_F2W, GS_F2W,
                           W.ff2_b + il * D_MODEL, GS_F2B,
                           W.ln2_w + il * D_MODEL, W.ln2_b + il * D_MODEL, GS_LN,
                           Xb + (size_t)m0 * D_MODEL, (unsigned long)Mpg * D_MODEL,
                           mc, DFF, nm, stream);
        }
    } else {
        // Last layer: only output rows are needed downstream.
        int Mc; unsigned long rsC;
        if (S >= 1024) { Mc = N_MASKED; rsC = (unsigned long)D_MODEL; }
        else           { Mc = Bpg;      rsC = (unsigned long)S * D_MODEL; }
        // fused out-proj(strided A) + residual(Xb strided) + LN1 -> XC1 (dense)
        launch_gemm_ln(O, rsC, (unsigned long)Mpg * D_MODEL,
                       Xb, rsC, (unsigned long)Mpg * D_MODEL,
                       W.outw + il * SZ_OUTW, GS_OUTW,
                       W.out_b + il * D_MODEL, GS_OUTB,
                       W.ln1_w + il * D_MODEL, W.ln1_b + il * D_MODEL, GS_LN,
                       XC1, (unsigned long)Mc * D_MODEL,
                       Mc, D_MODEL, nm, stream);
        launch_gemm(XC1, D_MODEL, W.f1w + il * SZ_F1W, W.ff1_b + il * DFF, FF,
                    Mc, DFF, D_MODEL, 1, nm,
                    (unsigned long)Mc * D_MODEL, GS_F1W, GS_F1B, (unsigned long)Mc * DFF,
                    stream);
        // fused FF2 + residual(XC1) + LN2 -> XC2
        launch_gemm_ln(FF, DFF, (unsigned long)Mc * DFF,
                       XC1, D_MODEL, (unsigned long)Mc * D_MODEL,
                       W.f2w + il * SZ_F2W, GS_F2W,
                       W.ff2_b + il * D_MODEL, GS_F2B,
                       W.ln2_w + il * D_MODEL, W.ln2_b + il * D_MODEL, GS_LN,
                       XC2, (unsigned long)Mc * D_MODEL,
                       Mc, DFF, nm, stream);
    }
}

static void run_encoder_g(unsigned short* Xb, unsigned short* QKV, unsigned short* O,
                          unsigned short* Tb, unsigned short* FF,
                          unsigned short* XC1, unsigned short* TC, unsigned short* XC2,
                          float* skAcc, float* skMS,
                          int ff_rows, int nm, int Btot, int S,
                          const int* lengths, const WB& W, int eid0, hipStream_t stream)
{
    for (int l = 0; l < DEPTH; ++l)
        run_layer_g(Xb, QKV, O, Tb, FF, XC1, TC, XC2, skAcc, skMS, ff_rows, nm, Btot, S,
                    lengths, W, eid0, l, l == DEPTH - 1, stream);
}

extern "C" void kernel_launch(void* const* d_in, const int* in_sizes, int n_in,
                              void* d_out, int out_size, void* d_ws, size_t ws_size,
                              hipStream_t stream)
{
    const float* tokens        = (const float*)d_in[0];
    const float* masked_tokens = (const float*)d_in[1];
    const float* hop_nodes     = (const float*)d_in[2];
    const float* level_nodes   = (const float*)d_in[3];
    const float* graph_nodes   = (const float*)d_in[4];
    const float* in_w  = (const float*)d_in[5];
    const float* in_b  = (const float*)d_in[6];
    const float* out_w = (const float*)d_in[7];
    const float* out_b = (const float*)d_in[8];
    const float* ff1_w = (const float*)d_in[9];
    const float* ff1_b = (const float*)d_in[10];
    const float* ff2_w = (const float*)d_in[11];
    const float* ff2_b = (const float*)d_in[12];
    const float* ln1_w = (const float*)d_in[13];
    const float* ln1_b = (const float*)d_in[14];
    const float* ln2_w = (const float*)d_in[15];
    const float* ln2_b = (const float*)d_in[16];
    const int* hop_list   = (const int*)d_in[17];
    const int* hop_lev    = (const int*)d_in[18];
    const int* hop_length = (const int*)d_in[19];

    float* ws = (float*)d_ws;
    size_t cap = ws_size / sizeof(float);
    const size_t MH = (size_t)NO_HOPS * (MAX_HOP_LEN + 1) * D_MODEL;

    const size_t N_INW  = (size_t)NLAY * SZ_INW;
    const size_t N_OUTW = (size_t)NLAY * SZ_OUTW;
    const size_t N_F1W  = (size_t)NLAY * SZ_F1W;
    const size_t N_F2W  = (size_t)NLAY * SZ_F2W;
    const size_t WBF = (N_INW + N_OUTW + N_F1W + N_F2W) / 2;
    const size_t SK_ACC = (size_t)NSPLIT * N_FINAL * HEADS * DH;
    const size_t SK_MS  = (size_t)NSPLIT * N_FINAL * HEADS * 2;
    const size_t SZC = (size_t)3 * N_MASKED * D_MODEL / 2;   // compact buf (floats)

    int NM = 3;
    {
        size_t fixed3 = 3 * MH / 2 + 3 * MH * 3 / 2 + 3 * MH / 2 + 3 * MH / 2
                      + (size_t)3 * NO_HOPS * D_MODEL + 3 * N_LEVELS * D_MODEL + 768 + 4096
                      + WBF + SK_ACC + SK_MS + 3 * SZC;
        size_t ffmin = (size_t)3 * 128 * DFF / 2;
        if (fixed3 + ffmin > cap) NM = 1;
    }

    size_t off = 0;
    auto take = [&](size_t n) { float* p = ws + off; off += (n + 7) & ~(size_t)7; return p; };
    size_t xsz = (size_t)NM * MH;
    unsigned short* Xb     = (unsigned short*)take(xsz / 2);
    unsigned short* QKV    = (unsigned short*)take(xsz * 3 / 2);
    unsigned short* O      = (unsigned short*)take(xsz / 2);
    unsigned short* Tb     = (unsigned short*)take(xsz / 2);
    float*          HOPTOK = take((size_t)3 * NO_HOPS * D_MODEL);
    float*          LEVTOK = take((size_t)3 * N_LEVELS * D_MODEL);
    float*          GTOK   = take((size_t)3 * D_MODEL);
    int*            POS    = (int*)take(2048);
    int*            COUNTS = POS + 3 * NO_HOPS;
    float*          SKACC  = take(SK_ACC);
    float*          SKMS   = take(SK_MS);
    unsigned short* XC1    = (unsigned short*)take(SZC);
    unsigned short* TC     = (unsigned short*)take(SZC);
    unsigned short* XC2    = (unsigned short*)take(SZC);
    unsigned short* WINW   = (unsigned short*)take(N_INW / 2);
    unsigned short* WOUTW  = (unsigned short*)take(N_OUTW / 2);
    unsigned short* WF1    = (unsigned short*)take(N_F1W / 2);
    unsigned short* WF2    = (unsigned short*)take(N_F2W / 2);
    unsigned short* FF     = (unsigned short*)(ws + off);
    size_t ff_ushorts = (cap > off) ? (cap - off) * 2 : 0;
    int ff_rows = (int)(ff_ushorts / ((size_t)NM * DFF));
    int max_rows = NO_HOPS * (MAX_HOP_LEN + 1);
    if (ff_rows > max_rows) ff_rows = max_rows;
    if (ff_rows > 2048) ff_rows &= ~127;
    if (ff_rows < 128) ff_rows = 128;

    hipLaunchKernelGGL(cvt_w, dim3((N_INW / 8 + 255) / 256), dim3(256), 0, stream, in_w,  WINW,  N_INW / 8);
    hipLaunchKernelGGL(cvt_w, dim3((N_OUTW / 8 + 255) / 256), dim3(256), 0, stream, out_w, WOUTW, N_OUTW / 8);
    hipLaunchKernelGGL(cvt_w, dim3((N_F1W / 8 + 255) / 256), dim3(256), 0, stream, ff1_w, WF1,   N_F1W / 8);
    hipLaunchKernelGGL(cvt_w, dim3((N_F2W / 8 + 255) / 256), dim3(256), 0, stream, ff2_w, WF2,   N_F2W / 8);

    WB W;
    W.inw = WINW; W.outw = WOUTW; W.f1w = WF1; W.f2w = WF2;
    W.in_b = in_b; W.out_b = out_b; W.ff1_b = ff1_b; W.ff2_b = ff2_b;
    W.ln1_w = ln1_w; W.ln1_b = ln1_b; W.ln2_w = ln2_w; W.ln2_b = ln2_b;

    for (int ms = 0; ms < 3; ms += NM) {
        const int nm = NM;
        {
            int total = nm * NO_HOPS * (MAX_HOP_LEN + 1) * D_MODEL;
            hipLaunchKernelGGL(build_hop_seq_g, dim3((total + 255) / 256), dim3(256), 0, stream,
                               tokens + (size_t)(ms + 1) * N_NODES * D_MODEL,
                               hop_list + (size_t)ms * NO_HOPS * MAX_HOP_LEN,
                               hop_nodes, Xb, nm);
        }
        run_encoder_g(Xb, QKV, O, Tb, FF, XC1, TC, XC2, SKACC, SKMS, ff_rows,
                      nm, nm * NO_HOPS, MAX_HOP_LEN + 1,
                      hop_length + (size_t)ms * NO_HOPS, W, 1 + ms, stream);
        {
            int B = nm * NO_HOPS;
            hipLaunchKernelGGL(extract_cls, dim3((B * D_MODEL + 255) / 256), dim3(256), 0, stream,
                               XC2, HOPTOK + (size_t)ms * NO_HOPS * D_MODEL, B, 1);
        }

        hipLaunchKernelGGL(compute_pos_g, dim3(nm), dim3(NO_HOPS), 0, stream,
                           hop_lev + (size_t)ms * NO_HOPS, POS, COUNTS);
        {
            int total = nm * N_LEVELS * (MAX_LEV_LEN + 1) * D_MODEL;
            hipLaunchKernelGGL(build_level_init_g, dim3((total + 255) / 256), dim3(256), 0, stream,
                               level_nodes, Xb, nm);
        }
        {
            int total = nm * NO_HOPS * D_MODEL;
            hipLaunchKernelGGL(scatter_hops_g, dim3((total + 255) / 256), dim3(256), 0, stream,
                               HOPTOK + (size_t)ms * NO_HOPS * D_MODEL,
                               hop_lev + (size_t)ms * NO_HOPS, POS, Xb, nm);
        }
        run_encoder_g(Xb, QKV, O, Tb, FF, XC1, TC, XC2, SKACC, SKMS, ff_rows,
                      nm, nm * N_LEVELS, MAX_LEV_LEN + 1,
                      COUNTS, W, 5 + ms, stream);
        {
            int B = nm * N_LEVELS;
            hipLaunchKernelGGL(extract_cls, dim3((B * D_MODEL + 255) / 256), dim3(256), 0, stream,
                               XC2, LEVTOK + (size_t)ms * N_LEVELS * D_MODEL, B, 1);
        }

        {
            int total = nm * (N_LEVELS + 1) * D_MODEL;
            hipLaunchKernelGGL(build_graph_seq_g, dim3((total + 255) / 256), dim3(256), 0, stream,
                               graph_nodes, LEVTOK + (size_t)ms * N_LEVELS * D_MODEL, Xb, nm);
        }
        run_encoder_g(Xb, QKV, O, Tb, FF, XC1, TC, XC2, SKACC, SKMS, ff_rows,
                      nm, nm, N_LEVELS + 1,
                      nullptr, W, 9 + ms, stream);
        {
            int B = nm;
            hipLaunchKernelGGL(extract_cls, dim3((B * D_MODEL + 255) / 256), dim3(256), 0, stream,
                               XC2, GTOK + (size_t)ms * D_MODEL, B, 1);
        }
    }

    {
        int total = N_FINAL * D_MODEL;
        hipLaunchKernelGGL(build_final_seq, dim3((total + 255) / 256), dim3(256), 0, stream,
                           masked_tokens, HOPTOK, LEVTOK, GTOK, Xb);
    }
    run_encoder_g(Xb, QKV, O, Tb, FF, XC1, TC, XC2, SKACC, SKMS, ff_rows,
                  1, 1, N_FINAL, nullptr, W, 12, stream);

    {
        int n = N_MASKED * D_MODEL;
        hipLaunchKernelGGL(copy_out_kernel, dim3((n + 255) / 256), dim3(256), 0, stream,
                           XC2, (float*)d_out, n);
    }
}

// Round 24
// 699.530 us; speedup vs baseline: 1.2732x; 1.2732x over previous
//
#include <hip/hip_runtime.h>

#define D_MODEL 256
#define HEADS 8
#define DH 32
#define DEPTH 2
#define DFF 2048
#define NO_HOPS 512
#define MAX_HOP_LEN 16
#define N_LEVELS 16
#define MAX_LEV_LEN 32
#define N_MASKED 512
#define N_NODES 8192
#define N_FINAL 2099   // 512 + 3*(512+16+1)
#define NLAY 26        // N_ENC * DEPTH
#define NSPLIT 8

typedef float f32x4 __attribute__((ext_vector_type(4)));
typedef short bf16x8 __attribute__((ext_vector_type(8)));
typedef short short4v __attribute__((ext_vector_type(4)));

#define GLOAD_LDS16(gp, lp) __builtin_amdgcn_global_load_lds( \
    (const __attribute__((address_space(1))) unsigned int*)(gp), \
    (__attribute__((address_space(3))) unsigned int*)(lp), 16, 0, 0)

__device__ __forceinline__ unsigned short f2bf(float f)
{
    unsigned int u = __builtin_bit_cast(unsigned int, f);
    unsigned int r = u + 0x7FFFu + ((u >> 16) & 1u);
    return (unsigned short)(r >> 16);
}

__device__ __forceinline__ float bf2f(unsigned short u)
{
    unsigned int x = (unsigned int)u << 16;
    return __builtin_bit_cast(float, x);
}

__device__ __forceinline__ bf16x8 cvt8(float4 a, float4 b)
{
    bf16x8 r;
    r[0] = (short)f2bf(a.x); r[1] = (short)f2bf(a.y);
    r[2] = (short)f2bf(a.z); r[3] = (short)f2bf(a.w);
    r[4] = (short)f2bf(b.x); r[5] = (short)f2bf(b.y);
    r[6] = (short)f2bf(b.z); r[7] = (short)f2bf(b.w);
    return r;
}

// ---------------- weight f32 -> bf16 conversion ----------------
__global__ void cvt_w(const float* __restrict__ src, unsigned short* __restrict__ dst, long n8)
{
    long i = (long)blockIdx.x * blockDim.x + threadIdx.x;
    if (i >= n8) return;
    const float4* s = reinterpret_cast<const float4*>(src) + i * 2;
    float4 a = s[0], b = s[1];
    *reinterpret_cast<bf16x8*>(dst + i * 8) = cvt8(a, b);
}

// ---------------- 64x128-tile GEMM: 48 KB LDS -> 3 blocks/CU ----------------------------
// rsA = element stride between consecutive A rows (rsA == K for dense; S*256 for CLS rows).
__global__ __launch_bounds__(256) void gemm_bb64(
    const unsigned short* __restrict__ A, const unsigned short* __restrict__ Wb,
    const float* __restrict__ bias, void* __restrict__ Yv,
    int M, int N, int K, int relu,
    unsigned long rsA, unsigned long xg, unsigned long wg, unsigned long bg, unsigned long yg)
{
    extern __shared__ unsigned short sh[];     // 24576 shorts = 48 KB
    const int grp = blockIdx.z;
    const int t = threadIdx.x;
    const int lane = t & 63, wid = t >> 6;
    const int wr = wid >> 1, wc = wid & 1;     // wave = 32 rows x 64 cols
    const int rowbase = blockIdx.y * 64;
    const int colbase = blockIdx.x * 128;
    const unsigned short* Abase = A + (size_t)grp * xg;
    const unsigned short* Wbase = Wb + (size_t)grp * wg;

    const unsigned short* gA[2]; unsigned short* lA[2];
    const unsigned short* gB[4]; unsigned short* lB[4];
    #pragma unroll
    for (int j = 0; j < 2; ++j) {
        int c = j * 256 + t;
        int sr = c >> 3, p = c & 7;
        int lc = p ^ (sr & 7);
        int ar = rowbase + sr; if (ar >= M) ar = M - 1;
        gA[j] = Abase + (size_t)ar * rsA + lc * 8;
        lA[j] = sh + (j * 256 + (t & ~63)) * 8;
    }
    #pragma unroll
    for (int j = 0; j < 4; ++j) {
        int c = j * 256 + t;
        int sr = c >> 3, p = c & 7;
        int lc = p ^ (sr & 7);
        gB[j] = Wbase + (size_t)(colbase + sr) * K + lc * 8;
        lB[j] = sh + 8192 + (j * 256 + (t & ~63)) * 8;
    }

    f32x4 acc[2][4];
    #pragma unroll
    for (int m = 0; m < 2; ++m)
        #pragma unroll
        for (int n = 0; n < 4; ++n)
            acc[m][n] = (f32x4){0.f, 0.f, 0.f, 0.f};

    const int g = lane >> 4, rr = lane & 15;
    const int nt = K >> 6;

    #pragma unroll
    for (int j = 0; j < 2; ++j) GLOAD_LDS16(gA[j], lA[j]);
    #pragma unroll
    for (int j = 0; j < 4; ++j) GLOAD_LDS16(gB[j], lB[j]);

    int buf = 0;
    for (int tt = 0; tt < nt; ++tt) {
        if (tt + 1 < nt) {
            const int k1 = (tt + 1) << 6;
            const int oa = (buf ^ 1) * 4096;
            const int ob = (buf ^ 1) * 8192;
            #pragma unroll
            for (int j = 0; j < 2; ++j) GLOAD_LDS16(gA[j] + k1, lA[j] + oa);
            #pragma unroll
            for (int j = 0; j < 4; ++j) GLOAD_LDS16(gB[j] + k1, lB[j] + ob);
            asm volatile("s_waitcnt vmcnt(6)\n\ts_barrier" ::: "memory");
        } else {
            asm volatile("s_waitcnt vmcnt(0)\n\ts_barrier" ::: "memory");
        }
        const unsigned short* Ab = sh + buf * 4096;
        const unsigned short* Bb = sh + 8192 + buf * 8192;
        #pragma unroll
        for (int ks = 0; ks < 2; ++ks) {
            bf16x8 af[2], bfr[4];
            #pragma unroll
            for (int m = 0; m < 2; ++m) {
                int row = wr * 32 + m * 16 + rr;
                int lc = ks * 4 + g;
                af[m] = *reinterpret_cast<const bf16x8*>(&Ab[row * 64 + ((lc ^ (row & 7)) * 8)]);
            }
            #pragma unroll
            for (int n = 0; n < 4; ++n) {
                int col = wc * 64 + n * 16 + rr;
                int lc = ks * 4 + g;
                bfr[n] = *reinterpret_cast<const bf16x8*>(&Bb[col * 64 + ((lc ^ (col & 7)) * 8)]);
            }
            #pragma unroll
            for (int m = 0; m < 2; ++m)
                #pragma unroll
                for (int n = 0; n < 4; ++n)
                    acc[m][n] = __builtin_amdgcn_mfma_f32_16x16x32_bf16(af[m], bfr[n], acc[m][n], 0, 0, 0);
        }
        asm volatile("s_barrier" ::: "memory");
        buf ^= 1;
    }

    const int rg = lane >> 4;
    const float* bp = bias + (size_t)grp * bg;
    #pragma unroll
    for (int n = 0; n < 4; ++n) {
        int coll = wc * 64 + n * 16 + rr;
        float bv = bp[colbase + coll];
        #pragma unroll
        for (int m = 0; m < 2; ++m) {
            #pragma unroll
            for (int i = 0; i < 4; ++i) {
                int rowl = wr * 32 + m * 16 + rg * 4 + i;
                float v = acc[m][n][i] + bv;
                if (relu) v = fmaxf(v, 0.f);
                sh[rowl * 128 + coll] = f2bf(v);
            }
        }
    }
    __syncthreads();
    unsigned short* Y = (unsigned short*)Yv + (size_t)grp * yg;
    int row = t >> 2, seg = t & 3;
    int grow = rowbase + row;
    if (grow < M) {
        const unsigned short* s = &sh[row * 128 + seg * 32];
        unsigned short* d = Y + (size_t)grow * N + colbase + seg * 32;
        #pragma unroll
        for (int j = 0; j < 4; ++j)
            *reinterpret_cast<bf16x8*>(d + j * 8) = *reinterpret_cast<const bf16x8*>(s + j * 8);
    }
}

// ---------------- small-S attention (S <= 32): one wave per (b,h), 4 per block ----------
__global__ __launch_bounds__(256) void attn_small(
    const unsigned short* __restrict__ QKV, const int* __restrict__ lengths,
    unsigned short* __restrict__ O, int B, int S)
{
    __shared__ __align__(16) unsigned short Ksm[4][32][40];
    __shared__ __align__(16) unsigned short Vsm[4][32][40];
    __shared__ __align__(16) unsigned short Psm[4][32][40];
    const int t = threadIdx.x;
    const int w = t >> 6, lane = t & 63;
    const int l15 = lane & 15, g = lane >> 4;
    int bh = blockIdx.x * 4 + w;
    const int BH = B * HEADS;
    if (bh >= BH) bh = BH - 1;
    const int b = bh >> 3, h = bh & 7;
    const unsigned short* base = QKV + (size_t)b * S * (3 * D_MODEL);
    int len_eff = S - 1;
    if (lengths) { int L = lengths[b]; if (L < len_eff) len_eff = L; }

    {
        int key = lane >> 1, hf = lane & 1;
        int kg = key < S ? key : S - 1;
        const unsigned short* kp = base + (size_t)kg * (3 * D_MODEL) + D_MODEL + h * DH + hf * 16;
        bf16x8 k0 = *reinterpret_cast<const bf16x8*>(kp);
        bf16x8 k1 = *reinterpret_cast<const bf16x8*>(kp + 8);
        *reinterpret_cast<bf16x8*>(&Ksm[w][key][hf * 16]) = k0;
        *reinterpret_cast<bf16x8*>(&Ksm[w][key][hf * 16 + 8]) = k1;
        const unsigned short* vp = kp + D_MODEL;
        bf16x8 v0 = *reinterpret_cast<const bf16x8*>(vp);
        bf16x8 v1 = *reinterpret_cast<const bf16x8*>(vp + 8);
        #pragma unroll
        for (int i = 0; i < 8; ++i) {
            Vsm[w][hf * 16 + i][key]     = (unsigned short)v0[i];
            Vsm[w][hf * 16 + 8 + i][key] = (unsigned short)v1[i];
        }
    }
    bf16x8 qa[2];
    #pragma unroll
    for (int qf = 0; qf < 2; ++qf) {
        int q = qf * 16 + l15; if (q > S - 1) q = S - 1;
        qa[qf] = *reinterpret_cast<const bf16x8*>(base + (size_t)q * (3 * D_MODEL) + h * DH + g * 8);
    }
    __syncthreads();

    const float scale = 0.17677669529663687f;
    const f32x4 zero = (f32x4){0.f,0.f,0.f,0.f};
    f32x4 sc[2][2];
    #pragma unroll
    for (int kf = 0; kf < 2; ++kf) {
        bf16x8 kb = *reinterpret_cast<const bf16x8*>(&Ksm[w][kf * 16 + l15][g * 8]);
        #pragma unroll
        for (int qf = 0; qf < 2; ++qf)
            sc[qf][kf] = __builtin_amdgcn_mfma_f32_16x16x32_bf16(qa[qf], kb, zero, 0, 0, 0);
    }
    float rsum[2][4];
    #pragma unroll
    for (int qf = 0; qf < 2; ++qf) {
        #pragma unroll
        for (int kf = 0; kf < 2; ++kf) {
            if (kf * 16 + l15 > len_eff) sc[qf][kf] = (f32x4){-1e9f,-1e9f,-1e9f,-1e9f};
            else sc[qf][kf] *= scale;
        }
        #pragma unroll
        for (int r = 0; r < 4; ++r) {
            float mx = fmaxf(sc[qf][0][r], sc[qf][1][r]);
            mx = fmaxf(mx, __shfl_xor(mx, 1, 64));
            mx = fmaxf(mx, __shfl_xor(mx, 2, 64));
            mx = fmaxf(mx, __shfl_xor(mx, 4, 64));
            mx = fmaxf(mx, __shfl_xor(mx, 8, 64));
            float s0 = __expf(sc[qf][0][r] - mx);
            float s1 = __expf(sc[qf][1][r] - mx);
            sc[qf][0][r] = s0;
            sc[qf][1][r] = s1;
            float ss = s0 + s1;
            ss += __shfl_xor(ss, 1, 64);
            ss += __shfl_xor(ss, 2, 64);
            ss += __shfl_xor(ss, 4, 64);
            ss += __shfl_xor(ss, 8, 64);
            rsum[qf][r] = ss;
        }
    }
    #pragma unroll
    for (int qf = 0; qf < 2; ++qf)
        #pragma unroll
        for (int kf = 0; kf < 2; ++kf)
            #pragma unroll
            for (int r = 0; r < 4; ++r)
                Psm[w][qf * 16 + g * 4 + r][kf * 16 + l15] = f2bf(sc[qf][kf][r]);
    __syncthreads();

    f32x4 o[2][2];
    #pragma unroll
    for (int df = 0; df < 2; ++df) {
        bf16x8 vb = *reinterpret_cast<const bf16x8*>(&Vsm[w][df * 16 + l15][g * 8]);
        #pragma unroll
        for (int qf = 0; qf < 2; ++qf) {
            bf16x8 pa = *reinterpret_cast<const bf16x8*>(&Psm[w][qf * 16 + l15][g * 8]);
            o[qf][df] = __builtin_amdgcn_mfma_f32_16x16x32_bf16(pa, vb, zero, 0, 0, 0);
        }
    }
    #pragma unroll
    for (int qf = 0; qf < 2; ++qf)
        #pragma unroll
        for (int r = 0; r < 4; ++r) {
            int q = qf * 16 + g * 4 + r;
            if (q < S) {
                float inv = 1.f / rsum[qf][r];
                #pragma unroll
                for (int df = 0; df < 2; ++df)
                    O[((size_t)b * S + q) * D_MODEL + h * DH + df * 16 + l15] = f2bf(o[qf][df][r] * inv);
            }
        }
}

// ---------------- MFMA flash attention; SPLIT=1: K-split partials (B must be 1) ----------
template<int SPLIT>
__global__ __launch_bounds__(256) void attn_flash(
    const unsigned short* __restrict__ QKV, const int* __restrict__ lengths,
    unsigned short* __restrict__ O, int B, int S,
    int NSv, float* __restrict__ pAcc, float* __restrict__ pMS)
{
    __shared__ __align__(16) unsigned short Kt[64][32];
    __shared__ __align__(16) unsigned short Vt[32][64];
    __shared__ __align__(16) unsigned short Pw[4][16][64];

    const int t = threadIdx.x;
    const int lane = t & 63, wid = t >> 6;
    const int l15 = lane & 15, g = lane >> 4;
    const int b = SPLIT ? 0 : blockIdx.z;
    const int sp = SPLIT ? blockIdx.z : 0;
    const int h = blockIdx.y;
    const int qb = blockIdx.x * 64 + wid * 16;
    const unsigned short* base = QKV + (size_t)b * S * (3 * D_MODEL);

    int len_eff = S - 1;
    if (lengths) { int L = lengths[b]; if (L < len_eff) len_eff = L; }

    const float scale = 0.17677669529663687f;
    int qrow = qb + l15; if (qrow > S - 1) qrow = S - 1;
    bf16x8 qa = *reinterpret_cast<const bf16x8*>(base + (size_t)qrow * (3 * D_MODEL) + h * DH + g * 8);

    float m[4], sum[4];
    f32x4 o[2];
    #pragma unroll
    for (int r = 0; r < 4; ++r) { m[r] = -3.0e38f; sum[r] = 0.f; }
    o[0] = (f32x4){0.f,0.f,0.f,0.f};
    o[1] = (f32x4){0.f,0.f,0.f,0.f};

    const int kl = t >> 2, cg = t & 3;
    const int ntiles_all = (S + 63) >> 6;
    int tstart = 0, tend = ntiles_all;
    if (SPLIT) {
        int chunkT = (ntiles_all + NSv - 1) / NSv;
        tstart = sp * chunkT;
        tend = tstart + chunkT;
        if (tend > ntiles_all) tend = ntiles_all;
    }

    for (int tt = tstart; tt < tend; ++tt) {
        const int kbase = tt * 64;
        {
            int key = kbase + kl; if (key > S - 1) key = S - 1;
            const unsigned short* kp = base + (size_t)key * (3 * D_MODEL) + D_MODEL + h * DH + cg * 8;
            *reinterpret_cast<bf16x8*>(&Kt[kl][cg * 8]) = *reinterpret_cast<const bf16x8*>(kp);
            bf16x8 vv = *reinterpret_cast<const bf16x8*>(kp + D_MODEL);
            #pragma unroll
            for (int i = 0; i < 8; ++i) {
                int d = cg * 8 + i;
                int c = ((kl >> 3) ^ (d & 7)) * 8 + (kl & 7);
                Vt[d][c] = (unsigned short)vv[i];
            }
        }
        __syncthreads();

        f32x4 sc[4];
        const f32x4 zero = (f32x4){0.f,0.f,0.f,0.f};
        #pragma unroll
        for (int f = 0; f < 4; ++f) {
            bf16x8 kf = *reinterpret_cast<const bf16x8*>(&Kt[f * 16 + l15][g * 8]);
            sc[f] = __builtin_amdgcn_mfma_f32_16x16x32_bf16(qa, kf, zero, 0, 0, 0);
            sc[f] *= scale;
        }
        #pragma unroll
        for (int f = 0; f < 4; ++f) {
            if (kbase + f * 16 + l15 > len_eff)
                sc[f] = (f32x4){-1e9f,-1e9f,-1e9f,-1e9f};
        }
        float cr[4];
        #pragma unroll
        for (int r = 0; r < 4; ++r) {
            float mx = fmaxf(fmaxf(sc[0][r], sc[1][r]), fmaxf(sc[2][r], sc[3][r]));
            mx = fmaxf(mx, __shfl_xor(mx, 1, 64));
            mx = fmaxf(mx, __shfl_xor(mx, 2, 64));
            mx = fmaxf(mx, __shfl_xor(mx, 4, 64));
            mx = fmaxf(mx, __shfl_xor(mx, 8, 64));
            float nm = fmaxf(m[r], mx);
            cr[r] = __expf(m[r] - nm);
            m[r] = nm;
            float ssum = 0.f;
            #pragma unroll
            for (int f = 0; f < 4; ++f) {
                float e = __expf(sc[f][r] - nm);
                sc[f][r] = e;
                ssum += e;
            }
            ssum += __shfl_xor(ssum, 1, 64);
            ssum += __shfl_xor(ssum, 2, 64);
            ssum += __shfl_xor(ssum, 4, 64);
            ssum += __shfl_xor(ssum, 8, 64);
            sum[r] = sum[r] * cr[r] + ssum;
            o[0][r] *= cr[r];
            o[1][r] *= cr[r];
        }
        #pragma unroll
        for (int f = 0; f < 4; ++f) {
            int chunk = f * 2 + (l15 >> 3);
            #pragma unroll
            for (int r = 0; r < 4; ++r) {
                int row = g * 4 + r;
                Pw[wid][row][(chunk ^ (row & 7)) * 8 + (l15 & 7)] = f2bf(sc[f][r]);
            }
        }
        #pragma unroll
        for (int s = 0; s < 2; ++s) {
            bf16x8 pa = *reinterpret_cast<const bf16x8*>(
                &Pw[wid][l15][((s * 4 + g) ^ (l15 & 7)) * 8]);
            #pragma unroll
            for (int jf = 0; jf < 2; ++jf) {
                int d = jf * 16 + l15;
                bf16x8 vb = *reinterpret_cast<const bf16x8*>(
                    &Vt[d][((s * 4 + g) ^ (d & 7)) * 8]);
                o[jf] = __builtin_amdgcn_mfma_f32_16x16x32_bf16(pa, vb, o[jf], 0, 0, 0);
            }
        }
        __syncthreads();
    }

    if (SPLIT) {
        #pragma unroll
        for (int r = 0; r < 4; ++r) {
            int qout = qb + g * 4 + r;
            if (qout < S) {
                size_t pb = ((size_t)qout * HEADS + h) * NSv + sp;
                pAcc[pb * 32 + l15]      = o[0][r];
                pAcc[pb * 32 + 16 + l15] = o[1][r];
                if (l15 == 0) { pMS[pb * 2] = m[r]; pMS[pb * 2 + 1] = sum[r]; }
            }
        }
    } else {
        #pragma unroll
        for (int r = 0; r < 4; ++r) {
            float inv = 1.f / sum[r];
            int qout = qb + g * 4 + r;
            if (qout < S) {
                #pragma unroll
                for (int jf = 0; jf < 2; ++jf)
                    O[((size_t)b * S + qout) * D_MODEL + h * DH + jf * 16 + l15] = f2bf(o[jf][r] * inv);
            }
        }
    }
}

// ---------------- split-K merge ----------------
__global__ void attn_merge(const float* __restrict__ pAcc, const float* __restrict__ pMS,
                           unsigned short* __restrict__ O, int S, int NS)
{
    int idx = blockIdx.x * blockDim.x + threadIdx.x;
    if (idx >= S * HEADS * DH) return;
    int d = idx & 31;
    int h = (idx >> 5) & 7;
    int q = idx >> 8;
    size_t base = ((size_t)q * HEADS + h) * NS;
    float mstar = -3.0e38f;
    for (int s = 0; s < NS; ++s) mstar = fmaxf(mstar, pMS[(base + s) * 2]);
    float ssum = 0.f, acc = 0.f;
    for (int s = 0; s < NS; ++s) {
        float mi = pMS[(base + s) * 2];
        float si = pMS[(base + s) * 2 + 1];
        float w = __expf(mi - mstar);
        ssum += si * w;
        acc += pAcc[(base + s) * 32 + d] * w;
    }
    O[(size_t)q * D_MODEL + h * DH + d] = f2bf(acc / ssum);
}

// ---------------- grouped residual add + LayerNorm; rsX = Xin row stride ----------------
__global__ void add_ln_g(const unsigned short* __restrict__ Xin, const unsigned short* __restrict__ R,
                         const float* __restrict__ w, const float* __restrict__ b,
                         unsigned short* __restrict__ Xout,
                         int M, int rows_pg, unsigned long wg, unsigned long rsX)
{
    int row = blockIdx.x * 4 + (threadIdx.x >> 6);
    int lane = threadIdx.x & 63;
    if (row >= M) return;
    int g = row / rows_pg;
    const float* wp = w + (size_t)g * wg;
    const float* bp = b + (size_t)g * wg;
    short4v xv = *reinterpret_cast<const short4v*>(Xin + (size_t)row * rsX + lane * 4);
    short4v rv = *reinterpret_cast<const short4v*>(R + (size_t)row * D_MODEL + lane * 4);
    float v[4];
    float sum = 0.f;
    #pragma unroll
    for (int j = 0; j < 4; ++j) {
        v[j] = bf2f((unsigned short)xv[j]) + bf2f((unsigned short)rv[j]);
        sum += v[j];
    }
    #pragma unroll
    for (int o = 32; o > 0; o >>= 1) sum += __shfl_xor(sum, o, 64);
    float mu = sum * (1.f / D_MODEL);
    float sq = 0.f;
    #pragma unroll
    for (int j = 0; j < 4; ++j) { float dd = v[j] - mu; sq += dd * dd; }
    #pragma unroll
    for (int o = 32; o > 0; o >>= 1) sq += __shfl_xor(sq, o, 64);
    float inv = rsqrtf(sq * (1.f / D_MODEL) + 1e-5f);
    short4v xb;
    #pragma unroll
    for (int j = 0; j < 4; ++j) {
        float out = (v[j] - mu) * inv * wp[lane * 4 + j] + bp[lane * 4 + j];
        xb[j] = (short)f2bf(out);
    }
    *reinterpret_cast<short4v*>(Xout + (size_t)row * D_MODEL + lane * 4) = xb;
}

// ---------------- builders (bf16 Xb only) ----------------
__global__ void build_hop_seq_g(const float* __restrict__ tok, const int* __restrict__ hlist,
                                const float* __restrict__ hop_nodes,
                                unsigned short* __restrict__ Xb, int nm)
{
    int idx = blockIdx.x * blockDim.x + threadIdx.x;
    const int per = NO_HOPS * (MAX_HOP_LEN + 1) * D_MODEL;
    if (idx >= nm * per) return;
    int g = idx / per, r = idx % per;
    int d = r & 255;
    int rest = r >> 8;
    int p = rest % (MAX_HOP_LEN + 1);
    int hh = rest / (MAX_HOP_LEN + 1);
    float v;
    if (p == 0) v = hop_nodes[d];
    else {
        int node = hlist[(size_t)g * NO_HOPS * MAX_HOP_LEN + hh * MAX_HOP_LEN + p - 1];
        v = tok[(size_t)g * N_NODES * D_MODEL + (size_t)node * D_MODEL + d];
    }
    Xb[idx] = f2bf(v);
}

__global__ void compute_pos_g(const int* __restrict__ hop_lev, int* __restrict__ pos,
                              int* __restrict__ counts)
{
    int g = blockIdx.x;
    const int* lev = hop_lev + (size_t)g * NO_HOPS;
    int i = threadIdx.x;
    int li = lev[i];
    int p = 0;
    for (int j = 0; j < i; ++j) p += (lev[j] == li);
    pos[(size_t)g * NO_HOPS + i] = p;
    if (i < N_LEVELS) {
        int c = 0;
        for (int j = 0; j < NO_HOPS; ++j) c += (lev[j] == i);
        counts[(size_t)g * N_LEVELS + i] = c;
    }
}

__global__ void build_level_init_g(const float* __restrict__ level_nodes,
                                   unsigned short* __restrict__ Gb, int nm)
{
    int idx = blockIdx.x * blockDim.x + threadIdx.x;
    const int per = N_LEVELS * (MAX_LEV_LEN + 1) * D_MODEL;
    if (idx >= nm * per) return;
    int r = idx % per;
    int d = r & 255;
    int p = (r >> 8) % (MAX_LEV_LEN + 1);
    float v = (p == 0) ? level_nodes[d] : 0.f;
    Gb[idx] = f2bf(v);
}

__global__ void scatter_hops_g(const float* __restrict__ hop_tok, const int* __restrict__ hop_lev,
                               const int* __restrict__ pos,
                               unsigned short* __restrict__ Gb, int nm)
{
    int idx = blockIdx.x * blockDim.x + threadIdx.x;
    const int per = NO_HOPS * D_MODEL;
    if (idx >= nm * per) return;
    int g = idx / per, r = idx % per;
    int d = r & 255;
    int i = r >> 8;
    int lv = hop_lev[(size_t)g * NO_HOPS + i];
    int ps = pos[(size_t)g * NO_HOPS + i];
    size_t dst = (size_t)g * N_LEVELS * (MAX_LEV_LEN + 1) * D_MODEL +
                 ((size_t)lv * (MAX_LEV_LEN + 1) + 1 + ps) * D_MODEL + d;
    Gb[dst] = f2bf(hop_tok[idx]);
}

__global__ void build_graph_seq_g(const float* __restrict__ graph_nodes,
                                  const float* __restrict__ lev_tok,
                                  unsigned short* __restrict__ Xb, int nm)
{
    int idx = blockIdx.x * blockDim.x + threadIdx.x;
    const int per = (N_LEVELS + 1) * D_MODEL;
    if (idx >= nm * per) return;
    int g = idx / per, r = idx % per;
    int d = r & 255;
    int p = r >> 8;
    float v = (p == 0) ? graph_nodes[d]
                       : lev_tok[(size_t)g * N_LEVELS * D_MODEL + (size_t)(p - 1) * D_MODEL + d];
    Xb[idx] = f2bf(v);
}

__global__ void build_final_seq(const float* __restrict__ masked, const float* __restrict__ hoptok,
                                const float* __restrict__ levtok, const float* __restrict__ gtok,
                                unsigned short* __restrict__ Xb)
{
    int idx = blockIdx.x * blockDim.x + threadIdx.x;
    const int total = N_FINAL * D_MODEL;
    if (idx >= total) return;
    int d = idx & 255;
    int r = idx >> 8;
    float v;
    if (r < N_MASKED) v = masked[idx];
    else {
        int t = r - N_MASKED;
        int m = t / 529;
        int w = t % 529;
        if (w < 512)      v = hoptok[((size_t)m * 512 + w) * D_MODEL + d];
        else if (w < 528) v = levtok[((size_t)m * 16 + (w - 512)) * D_MODEL + d];
        else              v = gtok[m * D_MODEL + d];
    }
    Xb[idx] = f2bf(v);
}

__global__ void extract_cls(const unsigned short* __restrict__ Xb, float* __restrict__ out,
                            int B, int S)
{
    int idx = blockIdx.x * blockDim.x + threadIdx.x;
    if (idx >= B * D_MODEL) return;
    int b = idx >> 8;
    int d = idx & 255;
    out[idx] = bf2f(Xb[(size_t)b * S * D_MODEL + d]);
}

__global__ void copy_out_kernel(const unsigned short* __restrict__ src, float* __restrict__ dst, int n)
{
    int i = blockIdx.x * blockDim.x + threadIdx.x;
    if (i < n) dst[i] = bf2f(src[i]);
}

// ---------------- host orchestration ----------------
struct WB {
    const unsigned short *inw, *outw, *f1w, *f2w;
    const float *in_b, *out_b, *ff1_b, *ff2_b, *ln1_w, *ln1_b, *ln2_w, *ln2_b;
};

#define SZ_INW  ((size_t)3 * D_MODEL * D_MODEL)
#define SZ_OUTW ((size_t)D_MODEL * D_MODEL)
#define SZ_F1W  ((size_t)DFF * D_MODEL)
#define SZ_F2W  ((size_t)D_MODEL * DFF)
#define GS_INW  ((unsigned long)DEPTH * SZ_INW)
#define GS_INB  ((unsigned long)DEPTH * 3 * D_MODEL)
#define GS_OUTW ((unsigned long)DEPTH * SZ_OUTW)
#define GS_OUTB ((unsigned long)DEPTH * D_MODEL)
#define GS_F1W  ((unsigned long)DEPTH * SZ_F1W)
#define GS_F1B  ((unsigned long)DEPTH * DFF)
#define GS_F2W  ((unsigned long)DEPTH * SZ_F2W)
#define GS_F2B  ((unsigned long)DEPTH * D_MODEL)
#define GS_LN   ((unsigned long)DEPTH * D_MODEL)

static void launch_gemm(const unsigned short* A, unsigned long rsA, const unsigned short* Wb,
                        const float* bias, void* Yv, int M, int N, int K, int relu, int nm,
                        unsigned long xg, unsigned long wg, unsigned long bg, unsigned long yg,
                        hipStream_t stream)
{
    dim3 grid(N / 128, (M + 63) / 64, nm);
    hipLaunchKernelGGL(gemm_bb64, grid, dim3(256), 49152, stream,
                       A, Wb, bias, Yv, M, N, K, relu, rsA, xg, wg, bg, yg);
}

static void run_layer_g(unsigned short* Xb, unsigned short* QKV, unsigned short* O,
                        unsigned short* Tb, unsigned short* FF,
                        unsigned short* XC1, unsigned short* TC, unsigned short* XC2,
                        float* skAcc, float* skMS,
                        int ff_rows, int nm, int Btot, int S,
                        const int* lengths, const WB& W, int eid0, int l, int last,
                        hipStream_t stream)
{
    const int Bpg = Btot / nm;
    const int Mpg = Bpg * S;
    const size_t il = (size_t)eid0 * DEPTH + l;
    // QKV: always full (K/V needed for all positions)
    launch_gemm(Xb, D_MODEL, W.inw + il * SZ_INW, W.in_b + il * 3 * D_MODEL, QKV,
                Mpg, 3 * D_MODEL, D_MODEL, 0, nm,
                (unsigned long)Mpg * D_MODEL, GS_INW, GS_INB, (unsigned long)Mpg * 3 * D_MODEL,
                stream);
    {
        int qspan = S;
        if (last && Btot == 1 && S >= 1024) qspan = N_MASKED;  // final encoder: only first 512 q rows
        int qtiles = (qspan + 63) / 64;
        if (S <= 32) {
            int blocks = (Btot * HEADS + 3) / 4;
            hipLaunchKernelGGL(attn_small, dim3(blocks), dim3(256), 0, stream,
                               QKV, lengths, O, Btot, S);
        } else if (Btot == 1 && S >= 1024) {
            dim3 grid(qtiles, HEADS, NSPLIT);
            hipLaunchKernelGGL((attn_flash<1>), grid, dim3(256), 0, stream,
                               QKV, lengths, O, Btot, S, NSPLIT, skAcc, skMS);
            int tot = qspan * HEADS * DH;
            hipLaunchKernelGGL(attn_merge, dim3((tot + 255) / 256), dim3(256), 0, stream,
                               skAcc, skMS, O, qspan, NSPLIT);
        } else {
            dim3 grid(qtiles, HEADS, Btot);
            hipLaunchKernelGGL((attn_flash<0>), grid, dim3(256), 0, stream,
                               QKV, lengths, O, Btot, S, 1, (float*)nullptr, (float*)nullptr);
        }
    }
    if (!last) {
        launch_gemm(O, D_MODEL, W.outw + il * SZ_OUTW, W.out_b + il * D_MODEL, Tb,
                    Mpg, D_MODEL, D_MODEL, 0, nm,
                    (unsigned long)Mpg * D_MODEL, GS_OUTW, GS_OUTB, (unsigned long)Mpg * D_MODEL,
                    stream);
        int Mtot = nm * Mpg;
        hipLaunchKernelGGL(add_ln_g, dim3((Mtot + 3) / 4), dim3(256), 0, stream,
                           Xb, Tb, W.ln1_w + il * D_MODEL, W.ln1_b + il * D_MODEL, Xb,
                           Mtot, Mpg, GS_LN, (unsigned long)D_MODEL);
        for (int m0 = 0; m0 < Mpg; m0 += ff_rows) {
            int mc = (Mpg - m0 < ff_rows) ? (Mpg - m0) : ff_rows;
            launch_gemm(Xb + (size_t)m0 * D_MODEL, D_MODEL,
                        W.f1w + il * SZ_F1W, W.ff1_b + il * DFF, FF,
                        mc, DFF, D_MODEL, 1, nm,
                        (unsigned long)Mpg * D_MODEL, GS_F1W, GS_F1B, (unsigned long)mc * DFF,
                        stream);
            launch_gemm(FF, DFF, W.f2w + il * SZ_F2W, W.ff2_b + il * D_MODEL,
                        Tb + (size_t)m0 * D_MODEL,
                        mc, D_MODEL, DFF, 0, nm,
                        (unsigned long)mc * DFF, GS_F2W, GS_F2B, (unsigned long)Mpg * D_MODEL,
                        stream);
        }
        hipLaunchKernelGGL(add_ln_g, dim3((Mtot + 3) / 4), dim3(256), 0, stream,
                           Xb, Tb, W.ln2_w + il * D_MODEL, W.ln2_b + il * D_MODEL, Xb,
                           Mtot, Mpg, GS_LN, (unsigned long)D_MODEL);
    } else {
        // Last layer: only output rows are needed downstream.
        // final encoder (S>=1024): prefix N_MASKED rows (stride 256); others: CLS row per sequence
        int Mc; unsigned long rsC;
        if (S >= 1024) { Mc = N_MASKED; rsC = (unsigned long)D_MODEL; }
        else           { Mc = Bpg;      rsC = (unsigned long)S * D_MODEL; }
        int Mtc = nm * Mc;
        launch_gemm(O, rsC, W.outw + il * SZ_OUTW, W.out_b + il * D_MODEL, TC,
                    Mc, D_MODEL, D_MODEL, 0, nm,
                    (unsigned long)Mpg * D_MODEL, GS_OUTW, GS_OUTB, (unsigned long)Mc * D_MODEL,
                    stream);
        hipLaunchKernelGGL(add_ln_g, dim3((Mtc + 3) / 4), dim3(256), 0, stream,
                           Xb, TC, W.ln1_w + il * D_MODEL, W.ln1_b + il * D_MODEL, XC1,
                           Mtc, Mc, GS_LN, rsC);
        launch_gemm(XC1, D_MODEL, W.f1w + il * SZ_F1W, W.ff1_b + il * DFF, FF,
                    Mc, DFF, D_MODEL, 1, nm,
                    (unsigned long)Mc * D_MODEL, GS_F1W, GS_F1B, (unsigned long)Mc * DFF,
                    stream);
        launch_gemm(FF, DFF, W.f2w + il * SZ_F2W, W.ff2_b + il * D_MODEL, TC,
                    Mc, D_MODEL, DFF, 0, nm,
                    (unsigned long)Mc * DFF, GS_F2W, GS_F2B, (unsigned long)Mc * D_MODEL,
                    stream);
        hipLaunchKernelGGL(add_ln_g, dim3((Mtc + 3) / 4), dim3(256), 0, stream,
                           XC1, TC, W.ln2_w + il * D_MODEL, W.ln2_b + il * D_MODEL, XC2,
                           Mtc, Mc, GS_LN, (unsigned long)D_MODEL);
    }
}

static void run_encoder_g(unsigned short* Xb, unsigned short* QKV, unsigned short* O,
                          unsigned short* Tb, unsigned short* FF,
                          unsigned short* XC1, unsigned short* TC, unsigned short* XC2,
                          float* skAcc, float* skMS,
                          int ff_rows, int nm, int Btot, int S,
                          const int* lengths, const WB& W, int eid0, hipStream_t stream)
{
    for (int l = 0; l < DEPTH; ++l)
        run_layer_g(Xb, QKV, O, Tb, FF, XC1, TC, XC2, skAcc, skMS, ff_rows, nm, Btot, S,
                    lengths, W, eid0, l, l == DEPTH - 1, stream);
}

extern "C" void kernel_launch(void* const* d_in, const int* in_sizes, int n_in,
                              void* d_out, int out_size, void* d_ws, size_t ws_size,
                              hipStream_t stream)
{
    const float* tokens        = (const float*)d_in[0];
    const float* masked_tokens = (const float*)d_in[1];
    const float* hop_nodes     = (const float*)d_in[2];
    const float* level_nodes   = (const float*)d_in[3];
    const float* graph_nodes   = (const float*)d_in[4];
    const float* in_w  = (const float*)d_in[5];
    const float* in_b  = (const float*)d_in[6];
    const float* out_w = (const float*)d_in[7];
    const float* out_b = (const float*)d_in[8];
    const float* ff1_w = (const float*)d_in[9];
    const float* ff1_b = (const float*)d_in[10];
    const float* ff2_w = (const float*)d_in[11];
    const float* ff2_b = (const float*)d_in[12];
    const float* ln1_w = (const float*)d_in[13];
    const float* ln1_b = (const float*)d_in[14];
    const float* ln2_w = (const float*)d_in[15];
    const float* ln2_b = (const float*)d_in[16];
    const int* hop_list   = (const int*)d_in[17];
    const int* hop_lev    = (const int*)d_in[18];
    const int* hop_length = (const int*)d_in[19];

    float* ws = (float*)d_ws;
    size_t cap = ws_size / sizeof(float);
    const size_t MH = (size_t)NO_HOPS * (MAX_HOP_LEN + 1) * D_MODEL;

    const size_t N_INW  = (size_t)NLAY * SZ_INW;
    const size_t N_OUTW = (size_t)NLAY * SZ_OUTW;
    const size_t N_F1W  = (size_t)NLAY * SZ_F1W;
    const size_t N_F2W  = (size_t)NLAY * SZ_F2W;
    const size_t WBF = (N_INW + N_OUTW + N_F1W + N_F2W) / 2;
    const size_t SK_ACC = (size_t)NSPLIT * N_FINAL * HEADS * DH;
    const size_t SK_MS  = (size_t)NSPLIT * N_FINAL * HEADS * 2;
    const size_t SZC = (size_t)3 * N_MASKED * D_MODEL / 2;   // compact buf (floats)

    int NM = 3;
    {
        size_t fixed3 = 3 * MH / 2 + 3 * MH * 3 / 2 + 3 * MH / 2 + 3 * MH / 2
                      + (size_t)3 * NO_HOPS * D_MODEL + 3 * N_LEVELS * D_MODEL + 768 + 4096
                      + WBF + SK_ACC + SK_MS + 3 * SZC;
        size_t ffmin = (size_t)3 * 128 * DFF / 2;
        if (fixed3 + ffmin > cap) NM = 1;
    }

    size_t off = 0;
    auto take = [&](size_t n) { float* p = ws + off; off += (n + 7) & ~(size_t)7; return p; };
    size_t xsz = (size_t)NM * MH;
    unsigned short* Xb     = (unsigned short*)take(xsz / 2);
    unsigned short* QKV    = (unsigned short*)take(xsz * 3 / 2);
    unsigned short* O      = (unsigned short*)take(xsz / 2);
    unsigned short* Tb     = (unsigned short*)take(xsz / 2);
    float*          HOPTOK = take((size_t)3 * NO_HOPS * D_MODEL);
    float*          LEVTOK = take((size_t)3 * N_LEVELS * D_MODEL);
    float*          GTOK   = take((size_t)3 * D_MODEL);
    int*            POS    = (int*)take(2048);
    int*            COUNTS = POS + 3 * NO_HOPS;
    float*          SKACC  = take(SK_ACC);
    float*          SKMS   = take(SK_MS);
    unsigned short* XC1    = (unsigned short*)take(SZC);
    unsigned short* TC     = (unsigned short*)take(SZC);
    unsigned short* XC2    = (unsigned short*)take(SZC);
    unsigned short* WINW   = (unsigned short*)take(N_INW / 2);
    unsigned short* WOUTW  = (unsigned short*)take(N_OUTW / 2);
    unsigned short* WF1    = (unsigned short*)take(N_F1W / 2);
    unsigned short* WF2    = (unsigned short*)take(N_F2W / 2);
    unsigned short* FF     = (unsigned short*)(ws + off);
    size_t ff_ushorts = (cap > off) ? (cap - off) * 2 : 0;
    int ff_rows = (int)(ff_ushorts / ((size_t)NM * DFF));
    int max_rows = NO_HOPS * (MAX_HOP_LEN + 1);
    if (ff_rows > max_rows) ff_rows = max_rows;
    if (ff_rows > 2048) ff_rows &= ~127;
    if (ff_rows < 128) ff_rows = 128;

    hipLaunchKernelGGL(cvt_w, dim3((N_INW / 8 + 255) / 256), dim3(256), 0, stream, in_w,  WINW,  N_INW / 8);
    hipLaunchKernelGGL(cvt_w, dim3((N_OUTW / 8 + 255) / 256), dim3(256), 0, stream, out_w, WOUTW, N_OUTW / 8);
    hipLaunchKernelGGL(cvt_w, dim3((N_F1W / 8 + 255) / 256), dim3(256), 0, stream, ff1_w, WF1,   N_F1W / 8);
    hipLaunchKernelGGL(cvt_w, dim3((N_F2W / 8 + 255) / 256), dim3(256), 0, stream, ff2_w, WF2,   N_F2W / 8);

    WB W;
    W.inw = WINW; W.outw = WOUTW; W.f1w = WF1; W.f2w = WF2;
    W.in_b = in_b; W.out_b = out_b; W.ff1_b = ff1_b; W.ff2_b = ff2_b;
    W.ln1_w = ln1_w; W.ln1_b = ln1_b; W.ln2_w = ln2_w; W.ln2_b = ln2_b;

    for (int ms = 0; ms < 3; ms += NM) {
        const int nm = NM;
        {
            int total = nm * NO_HOPS * (MAX_HOP_LEN + 1) * D_MODEL;
            hipLaunchKernelGGL(build_hop_seq_g, dim3((total + 255) / 256), dim3(256), 0, stream,
                               tokens + (size_t)(ms + 1) * N_NODES * D_MODEL,
                               hop_list + (size_t)ms * NO_HOPS * MAX_HOP_LEN,
                               hop_nodes, Xb, nm);
        }
        run_encoder_g(Xb, QKV, O, Tb, FF, XC1, TC, XC2, SKACC, SKMS, ff_rows,
                      nm, nm * NO_HOPS, MAX_HOP_LEN + 1,
                      hop_length + (size_t)ms * NO_HOPS, W, 1 + ms, stream);
        {
            int B = nm * NO_HOPS;
            hipLaunchKernelGGL(extract_cls, dim3((B * D_MODEL + 255) / 256), dim3(256), 0, stream,
                               XC2, HOPTOK + (size_t)ms * NO_HOPS * D_MODEL, B, 1);
        }

        hipLaunchKernelGGL(compute_pos_g, dim3(nm), dim3(NO_HOPS), 0, stream,
                           hop_lev + (size_t)ms * NO_HOPS, POS, COUNTS);
        {
            int total = nm * N_LEVELS * (MAX_LEV_LEN + 1) * D_MODEL;
            hipLaunchKernelGGL(build_level_init_g, dim3((total + 255) / 256), dim3(256), 0, stream,
                               level_nodes, Xb, nm);
        }
        {
            int total = nm * NO_HOPS * D_MODEL;
            hipLaunchKernelGGL(scatter_hops_g, dim3((total + 255) / 256), dim3(256), 0, stream,
                               HOPTOK + (size_t)ms * NO_HOPS * D_MODEL,
                               hop_lev + (size_t)ms * NO_HOPS, POS, Xb, nm);
        }
        run_encoder_g(Xb, QKV, O, Tb, FF, XC1, TC, XC2, SKACC, SKMS, ff_rows,
                      nm, nm * N_LEVELS, MAX_LEV_LEN + 1,
                      COUNTS, W, 5 + ms, stream);
        {
            int B = nm * N_LEVELS;
            hipLaunchKernelGGL(extract_cls, dim3((B * D_MODEL + 255) / 256), dim3(256), 0, stream,
                               XC2, LEVTOK + (size_t)ms * N_LEVELS * D_MODEL, B, 1);
        }

        {
            int total = nm * (N_LEVELS + 1) * D_MODEL;
            hipLaunchKernelGGL(build_graph_seq_g, dim3((total + 255) / 256), dim3(256), 0, stream,
                               graph_nodes, LEVTOK + (size_t)ms * N_LEVELS * D_MODEL, Xb, nm);
        }
        run_encoder_g(Xb, QKV, O, Tb, FF, XC1, TC, XC2, SKACC, SKMS, ff_rows,
                      nm, nm, N_LEVELS + 1,
                      nullptr, W, 9 + ms, stream);
        {
            int B = nm;
            hipLaunchKernelGGL(extract_cls, dim3((B * D_MODEL + 255) / 256), dim3(256), 0, stream,
                               XC2, GTOK + (size_t)ms * D_MODEL, B, 1);
        }
    }

    {
        int total = N_FINAL * D_MODEL;
        hipLaunchKernelGGL(build_final_seq, dim3((total + 255) / 256), dim3(256), 0, stream,
                           masked_tokens, HOPTOK, LEVTOK, GTOK, Xb);
    }
    run_encoder_g(Xb, QKV, O, Tb, FF, XC1, TC, XC2, SKACC, SKMS, ff_rows,
                  1, 1, N_FINAL, nullptr, W, 12, stream);

    {
        int n = N_MASKED * D_MODEL;
        hipLaunchKernelGGL(copy_out_kernel, dim3((n + 255) / 256), dim3(256), 0, stream,
                           XC2, (float*)d_out, n);
    }
}

// Round 25
// 682.841 us; speedup vs baseline: 1.3043x; 1.0244x over previous
//
#include <hip/hip_runtime.h>

#define D_MODEL 256
#define HEADS 8
#define DH 32
#define DEPTH 2
#define DFF 2048
#define NO_HOPS 512
#define MAX_HOP_LEN 16
#define N_LEVELS 16
#define MAX_LEV_LEN 32
#define N_MASKED 512
#define N_NODES 8192
#define N_FINAL 2099   // 512 + 3*(512+16+1)
#define NLAY 26        // N_ENC * DEPTH
#define NSPLIT 8

typedef float f32x4 __attribute__((ext_vector_type(4)));
typedef short bf16x8 __attribute__((ext_vector_type(8)));
typedef short short4v __attribute__((ext_vector_type(4)));

#define GLOAD_LDS16(gp, lp) __builtin_amdgcn_global_load_lds( \
    (const __attribute__((address_space(1))) unsigned int*)(gp), \
    (__attribute__((address_space(3))) unsigned int*)(lp), 16, 0, 0)

__device__ __forceinline__ unsigned short f2bf(float f)
{
    unsigned int u = __builtin_bit_cast(unsigned int, f);
    unsigned int r = u + 0x7FFFu + ((u >> 16) & 1u);
    return (unsigned short)(r >> 16);
}

__device__ __forceinline__ float bf2f(unsigned short u)
{
    unsigned int x = (unsigned int)u << 16;
    return __builtin_bit_cast(float, x);
}

__device__ __forceinline__ bf16x8 cvt8(float4 a, float4 b)
{
    bf16x8 r;
    r[0] = (short)f2bf(a.x); r[1] = (short)f2bf(a.y);
    r[2] = (short)f2bf(a.z); r[3] = (short)f2bf(a.w);
    r[4] = (short)f2bf(b.x); r[5] = (short)f2bf(b.y);
    r[6] = (short)f2bf(b.z); r[7] = (short)f2bf(b.w);
    return r;
}

// ---------------- weight f32 -> bf16 conversion (4 arrays fused) ----------------
__global__ void cvt_w4(const float* __restrict__ s0, unsigned short* __restrict__ d0, long n0,
                       const float* __restrict__ s1, unsigned short* __restrict__ d1, long n1,
                       const float* __restrict__ s2, unsigned short* __restrict__ d2, long n2,
                       const float* __restrict__ s3, unsigned short* __restrict__ d3, long n3)
{
    long i = (long)blockIdx.x * blockDim.x + threadIdx.x;
    const float* s; unsigned short* d; long k;
    if (i < n0)                     { s = s0; d = d0; k = i; }
    else if (i < n0 + n1)           { s = s1; d = d1; k = i - n0; }
    else if (i < n0 + n1 + n2)      { s = s2; d = d2; k = i - n0 - n1; }
    else if (i < n0 + n1 + n2 + n3) { s = s3; d = d3; k = i - n0 - n1 - n2; }
    else return;
    const float4* sp = reinterpret_cast<const float4*>(s) + k * 2;
    *reinterpret_cast<bf16x8*>(d + k * 8) = cvt8(sp[0], sp[1]);
}

// ---------------- 64x128-tile GEMM: 48 KB LDS -> 3 blocks/CU ----------------------------
// rsA = element stride between consecutive A rows (rsA == K for dense; S*256 for CLS rows).
__global__ __launch_bounds__(256) void gemm_bb64(
    const unsigned short* __restrict__ A, const unsigned short* __restrict__ Wb,
    const float* __restrict__ bias, void* __restrict__ Yv,
    int M, int N, int K, int relu,
    unsigned long rsA, unsigned long xg, unsigned long wg, unsigned long bg, unsigned long yg)
{
    extern __shared__ unsigned short sh[];     // 24576 shorts = 48 KB
    const int grp = blockIdx.z;
    const int t = threadIdx.x;
    const int lane = t & 63, wid = t >> 6;
    const int wr = wid >> 1, wc = wid & 1;     // wave = 32 rows x 64 cols
    const int rowbase = blockIdx.y * 64;
    const int colbase = blockIdx.x * 128;
    const unsigned short* Abase = A + (size_t)grp * xg;
    const unsigned short* Wbase = Wb + (size_t)grp * wg;

    const unsigned short* gA[2]; unsigned short* lA[2];
    const unsigned short* gB[4]; unsigned short* lB[4];
    #pragma unroll
    for (int j = 0; j < 2; ++j) {
        int c = j * 256 + t;
        int sr = c >> 3, p = c & 7;
        int lc = p ^ (sr & 7);
        int ar = rowbase + sr; if (ar >= M) ar = M - 1;
        gA[j] = Abase + (size_t)ar * rsA + lc * 8;
        lA[j] = sh + (j * 256 + (t & ~63)) * 8;
    }
    #pragma unroll
    for (int j = 0; j < 4; ++j) {
        int c = j * 256 + t;
        int sr = c >> 3, p = c & 7;
        int lc = p ^ (sr & 7);
        gB[j] = Wbase + (size_t)(colbase + sr) * K + lc * 8;
        lB[j] = sh + 8192 + (j * 256 + (t & ~63)) * 8;
    }

    f32x4 acc[2][4];
    #pragma unroll
    for (int m = 0; m < 2; ++m)
        #pragma unroll
        for (int n = 0; n < 4; ++n)
            acc[m][n] = (f32x4){0.f, 0.f, 0.f, 0.f};

    const int g = lane >> 4, rr = lane & 15;
    const int nt = K >> 6;

    #pragma unroll
    for (int j = 0; j < 2; ++j) GLOAD_LDS16(gA[j], lA[j]);
    #pragma unroll
    for (int j = 0; j < 4; ++j) GLOAD_LDS16(gB[j], lB[j]);

    int buf = 0;
    for (int tt = 0; tt < nt; ++tt) {
        if (tt + 1 < nt) {
            const int k1 = (tt + 1) << 6;
            const int oa = (buf ^ 1) * 4096;
            const int ob = (buf ^ 1) * 8192;
            #pragma unroll
            for (int j = 0; j < 2; ++j) GLOAD_LDS16(gA[j] + k1, lA[j] + oa);
            #pragma unroll
            for (int j = 0; j < 4; ++j) GLOAD_LDS16(gB[j] + k1, lB[j] + ob);
            asm volatile("s_waitcnt vmcnt(6)\n\ts_barrier" ::: "memory");
        } else {
            asm volatile("s_waitcnt vmcnt(0)\n\ts_barrier" ::: "memory");
        }
        const unsigned short* Ab = sh + buf * 4096;
        const unsigned short* Bb = sh + 8192 + buf * 8192;
        #pragma unroll
        for (int ks = 0; ks < 2; ++ks) {
            bf16x8 af[2], bfr[4];
            #pragma unroll
            for (int m = 0; m < 2; ++m) {
                int row = wr * 32 + m * 16 + rr;
                int lc = ks * 4 + g;
                af[m] = *reinterpret_cast<const bf16x8*>(&Ab[row * 64 + ((lc ^ (row & 7)) * 8)]);
            }
            #pragma unroll
            for (int n = 0; n < 4; ++n) {
                int col = wc * 64 + n * 16 + rr;
                int lc = ks * 4 + g;
                bfr[n] = *reinterpret_cast<const bf16x8*>(&Bb[col * 64 + ((lc ^ (col & 7)) * 8)]);
            }
            #pragma unroll
            for (int m = 0; m < 2; ++m)
                #pragma unroll
                for (int n = 0; n < 4; ++n)
                    acc[m][n] = __builtin_amdgcn_mfma_f32_16x16x32_bf16(af[m], bfr[n], acc[m][n], 0, 0, 0);
        }
        asm volatile("s_barrier" ::: "memory");
        buf ^= 1;
    }

    const int rg = lane >> 4;
    const float* bp = bias + (size_t)grp * bg;
    #pragma unroll
    for (int n = 0; n < 4; ++n) {
        int coll = wc * 64 + n * 16 + rr;
        float bv = bp[colbase + coll];
        #pragma unroll
        for (int m = 0; m < 2; ++m) {
            #pragma unroll
            for (int i = 0; i < 4; ++i) {
                int rowl = wr * 32 + m * 16 + rg * 4 + i;
                float v = acc[m][n][i] + bv;
                if (relu) v = fmaxf(v, 0.f);
                sh[rowl * 128 + coll] = f2bf(v);
            }
        }
    }
    __syncthreads();
    unsigned short* Y = (unsigned short*)Yv + (size_t)grp * yg;
    int row = t >> 2, seg = t & 3;
    int grow = rowbase + row;
    if (grow < M) {
        const unsigned short* s = &sh[row * 128 + seg * 32];
        unsigned short* d = Y + (size_t)grow * N + colbase + seg * 32;
        #pragma unroll
        for (int j = 0; j < 4; ++j)
            *reinterpret_cast<bf16x8*>(d + j * 8) = *reinterpret_cast<const bf16x8*>(s + j * 8);
    }
}

// ---------------- small-S attention (S <= 32): one wave per (b,h), 4 per block ----------
__global__ __launch_bounds__(256) void attn_small(
    const unsigned short* __restrict__ QKV, const int* __restrict__ lengths,
    unsigned short* __restrict__ O, int B, int S)
{
    __shared__ __align__(16) unsigned short Ksm[4][32][40];
    __shared__ __align__(16) unsigned short Vsm[4][32][40];
    __shared__ __align__(16) unsigned short Psm[4][32][40];
    const int t = threadIdx.x;
    const int w = t >> 6, lane = t & 63;
    const int l15 = lane & 15, g = lane >> 4;
    int bh = blockIdx.x * 4 + w;
    const int BH = B * HEADS;
    if (bh >= BH) bh = BH - 1;
    const int b = bh >> 3, h = bh & 7;
    const unsigned short* base = QKV + (size_t)b * S * (3 * D_MODEL);
    int len_eff = S - 1;
    if (lengths) { int L = lengths[b]; if (L < len_eff) len_eff = L; }

    {
        int key = lane >> 1, hf = lane & 1;
        int kg = key < S ? key : S - 1;
        const unsigned short* kp = base + (size_t)kg * (3 * D_MODEL) + D_MODEL + h * DH + hf * 16;
        bf16x8 k0 = *reinterpret_cast<const bf16x8*>(kp);
        bf16x8 k1 = *reinterpret_cast<const bf16x8*>(kp + 8);
        *reinterpret_cast<bf16x8*>(&Ksm[w][key][hf * 16]) = k0;
        *reinterpret_cast<bf16x8*>(&Ksm[w][key][hf * 16 + 8]) = k1;
        const unsigned short* vp = kp + D_MODEL;
        bf16x8 v0 = *reinterpret_cast<const bf16x8*>(vp);
        bf16x8 v1 = *reinterpret_cast<const bf16x8*>(vp + 8);
        #pragma unroll
        for (int i = 0; i < 8; ++i) {
            Vsm[w][hf * 16 + i][key]     = (unsigned short)v0[i];
            Vsm[w][hf * 16 + 8 + i][key] = (unsigned short)v1[i];
        }
    }
    bf16x8 qa[2];
    #pragma unroll
    for (int qf = 0; qf < 2; ++qf) {
        int q = qf * 16 + l15; if (q > S - 1) q = S - 1;
        qa[qf] = *reinterpret_cast<const bf16x8*>(base + (size_t)q * (3 * D_MODEL) + h * DH + g * 8);
    }
    __syncthreads();

    const float scale = 0.17677669529663687f;
    const f32x4 zero = (f32x4){0.f,0.f,0.f,0.f};
    f32x4 sc[2][2];
    #pragma unroll
    for (int kf = 0; kf < 2; ++kf) {
        bf16x8 kb = *reinterpret_cast<const bf16x8*>(&Ksm[w][kf * 16 + l15][g * 8]);
        #pragma unroll
        for (int qf = 0; qf < 2; ++qf)
            sc[qf][kf] = __builtin_amdgcn_mfma_f32_16x16x32_bf16(qa[qf], kb, zero, 0, 0, 0);
    }
    float rsum[2][4];
    #pragma unroll
    for (int qf = 0; qf < 2; ++qf) {
        #pragma unroll
        for (int kf = 0; kf < 2; ++kf) {
            if (kf * 16 + l15 > len_eff) sc[qf][kf] = (f32x4){-1e9f,-1e9f,-1e9f,-1e9f};
            else sc[qf][kf] *= scale;
        }
        #pragma unroll
        for (int r = 0; r < 4; ++r) {
            float mx = fmaxf(sc[qf][0][r], sc[qf][1][r]);
            mx = fmaxf(mx, __shfl_xor(mx, 1, 64));
            mx = fmaxf(mx, __shfl_xor(mx, 2, 64));
            mx = fmaxf(mx, __shfl_xor(mx, 4, 64));
            mx = fmaxf(mx, __shfl_xor(mx, 8, 64));
            float s0 = __expf(sc[qf][0][r] - mx);
            float s1 = __expf(sc[qf][1][r] - mx);
            sc[qf][0][r] = s0;
            sc[qf][1][r] = s1;
            float ss = s0 + s1;
            ss += __shfl_xor(ss, 1, 64);
            ss += __shfl_xor(ss, 2, 64);
            ss += __shfl_xor(ss, 4, 64);
            ss += __shfl_xor(ss, 8, 64);
            rsum[qf][r] = ss;
        }
    }
    #pragma unroll
    for (int qf = 0; qf < 2; ++qf)
        #pragma unroll
        for (int kf = 0; kf < 2; ++kf)
            #pragma unroll
            for (int r = 0; r < 4; ++r)
                Psm[w][qf * 16 + g * 4 + r][kf * 16 + l15] = f2bf(sc[qf][kf][r]);
    __syncthreads();

    f32x4 o[2][2];
    #pragma unroll
    for (int df = 0; df < 2; ++df) {
        bf16x8 vb = *reinterpret_cast<const bf16x8*>(&Vsm[w][df * 16 + l15][g * 8]);
        #pragma unroll
        for (int qf = 0; qf < 2; ++qf) {
            bf16x8 pa = *reinterpret_cast<const bf16x8*>(&Psm[w][qf * 16 + l15][g * 8]);
            o[qf][df] = __builtin_amdgcn_mfma_f32_16x16x32_bf16(pa, vb, zero, 0, 0, 0);
        }
    }
    #pragma unroll
    for (int qf = 0; qf < 2; ++qf)
        #pragma unroll
        for (int r = 0; r < 4; ++r) {
            int q = qf * 16 + g * 4 + r;
            if (q < S) {
                float inv = 1.f / rsum[qf][r];
                #pragma unroll
                for (int df = 0; df < 2; ++df)
                    O[((size_t)b * S + q) * D_MODEL + h * DH + df * 16 + l15] = f2bf(o[qf][df][r] * inv);
            }
        }
}

// ---------------- MFMA flash attention; SPLIT=1: K-split partials (B must be 1) ----------
template<int SPLIT>
__global__ __launch_bounds__(256) void attn_flash(
    const unsigned short* __restrict__ QKV, const int* __restrict__ lengths,
    unsigned short* __restrict__ O, int B, int S,
    int NSv, float* __restrict__ pAcc, float* __restrict__ pMS)
{
    __shared__ __align__(16) unsigned short Kt[64][32];
    __shared__ __align__(16) unsigned short Vt[32][64];
    __shared__ __align__(16) unsigned short Pw[4][16][64];

    const int t = threadIdx.x;
    const int lane = t & 63, wid = t >> 6;
    const int l15 = lane & 15, g = lane >> 4;
    const int b = SPLIT ? 0 : blockIdx.z;
    const int sp = SPLIT ? blockIdx.z : 0;
    const int h = blockIdx.y;
    const int qb = blockIdx.x * 64 + wid * 16;
    const unsigned short* base = QKV + (size_t)b * S * (3 * D_MODEL);

    int len_eff = S - 1;
    if (lengths) { int L = lengths[b]; if (L < len_eff) len_eff = L; }

    const float scale = 0.17677669529663687f;
    int qrow = qb + l15; if (qrow > S - 1) qrow = S - 1;
    bf16x8 qa = *reinterpret_cast<const bf16x8*>(base + (size_t)qrow * (3 * D_MODEL) + h * DH + g * 8);

    float m[4], sum[4];
    f32x4 o[2];
    #pragma unroll
    for (int r = 0; r < 4; ++r) { m[r] = -3.0e38f; sum[r] = 0.f; }
    o[0] = (f32x4){0.f,0.f,0.f,0.f};
    o[1] = (f32x4){0.f,0.f,0.f,0.f};

    const int kl = t >> 2, cg = t & 3;
    const int ntiles_all = (S + 63) >> 6;
    int tstart = 0, tend = ntiles_all;
    if (SPLIT) {
        int chunkT = (ntiles_all + NSv - 1) / NSv;
        tstart = sp * chunkT;
        tend = tstart + chunkT;
        if (tend > ntiles_all) tend = ntiles_all;
    }

    for (int tt = tstart; tt < tend; ++tt) {
        const int kbase = tt * 64;
        {
            int key = kbase + kl; if (key > S - 1) key = S - 1;
            const unsigned short* kp = base + (size_t)key * (3 * D_MODEL) + D_MODEL + h * DH + cg * 8;
            *reinterpret_cast<bf16x8*>(&Kt[kl][cg * 8]) = *reinterpret_cast<const bf16x8*>(kp);
            bf16x8 vv = *reinterpret_cast<const bf16x8*>(kp + D_MODEL);
            #pragma unroll
            for (int i = 0; i < 8; ++i) {
                int d = cg * 8 + i;
                int c = ((kl >> 3) ^ (d & 7)) * 8 + (kl & 7);
                Vt[d][c] = (unsigned short)vv[i];
            }
        }
        __syncthreads();

        f32x4 sc[4];
        const f32x4 zero = (f32x4){0.f,0.f,0.f,0.f};
        #pragma unroll
        for (int f = 0; f < 4; ++f) {
            bf16x8 kf = *reinterpret_cast<const bf16x8*>(&Kt[f * 16 + l15][g * 8]);
            sc[f] = __builtin_amdgcn_mfma_f32_16x16x32_bf16(qa, kf, zero, 0, 0, 0);
            sc[f] *= scale;
        }
        #pragma unroll
        for (int f = 0; f < 4; ++f) {
            if (kbase + f * 16 + l15 > len_eff)
                sc[f] = (f32x4){-1e9f,-1e9f,-1e9f,-1e9f};
        }
        float cr[4];
        #pragma unroll
        for (int r = 0; r < 4; ++r) {
            float mx = fmaxf(fmaxf(sc[0][r], sc[1][r]), fmaxf(sc[2][r], sc[3][r]));
            mx = fmaxf(mx, __shfl_xor(mx, 1, 64));
            mx = fmaxf(mx, __shfl_xor(mx, 2, 64));
            mx = fmaxf(mx, __shfl_xor(mx, 4, 64));
            mx = fmaxf(mx, __shfl_xor(mx, 8, 64));
            float nm = fmaxf(m[r], mx);
            cr[r] = __expf(m[r] - nm);
            m[r] = nm;
            float ssum = 0.f;
            #pragma unroll
            for (int f = 0; f < 4; ++f) {
                float e = __expf(sc[f][r] - nm);
                sc[f][r] = e;
                ssum += e;
            }
            ssum += __shfl_xor(ssum, 1, 64);
            ssum += __shfl_xor(ssum, 2, 64);
            ssum += __shfl_xor(ssum, 4, 64);
            ssum += __shfl_xor(ssum, 8, 64);
            sum[r] = sum[r] * cr[r] + ssum;
            o[0][r] *= cr[r];
            o[1][r] *= cr[r];
        }
        #pragma unroll
        for (int f = 0; f < 4; ++f) {
            int chunk = f * 2 + (l15 >> 3);
            #pragma unroll
            for (int r = 0; r < 4; ++r) {
                int row = g * 4 + r;
                Pw[wid][row][(chunk ^ (row & 7)) * 8 + (l15 & 7)] = f2bf(sc[f][r]);
            }
        }
        #pragma unroll
        for (int s = 0; s < 2; ++s) {
            bf16x8 pa = *reinterpret_cast<const bf16x8*>(
                &Pw[wid][l15][((s * 4 + g) ^ (l15 & 7)) * 8]);
            #pragma unroll
            for (int jf = 0; jf < 2; ++jf) {
                int d = jf * 16 + l15;
                bf16x8 vb = *reinterpret_cast<const bf16x8*>(
                    &Vt[d][((s * 4 + g) ^ (d & 7)) * 8]);
                o[jf] = __builtin_amdgcn_mfma_f32_16x16x32_bf16(pa, vb, o[jf], 0, 0, 0);
            }
        }
        __syncthreads();
    }

    if (SPLIT) {
        #pragma unroll
        for (int r = 0; r < 4; ++r) {
            int qout = qb + g * 4 + r;
            if (qout < S) {
                size_t pb = ((size_t)qout * HEADS + h) * NSv + sp;
                pAcc[pb * 32 + l15]      = o[0][r];
                pAcc[pb * 32 + 16 + l15] = o[1][r];
                if (l15 == 0) { pMS[pb * 2] = m[r]; pMS[pb * 2 + 1] = sum[r]; }
            }
        }
    } else {
        #pragma unroll
        for (int r = 0; r < 4; ++r) {
            float inv = 1.f / sum[r];
            int qout = qb + g * 4 + r;
            if (qout < S) {
                #pragma unroll
                for (int jf = 0; jf < 2; ++jf)
                    O[((size_t)b * S + qout) * D_MODEL + h * DH + jf * 16 + l15] = f2bf(o[jf][r] * inv);
            }
        }
    }
}

// ---------------- split-K merge ----------------
__global__ void attn_merge(const float* __restrict__ pAcc, const float* __restrict__ pMS,
                           unsigned short* __restrict__ O, int S, int NS)
{
    int idx = blockIdx.x * blockDim.x + threadIdx.x;
    if (idx >= S * HEADS * DH) return;
    int d = idx & 31;
    int h = (idx >> 5) & 7;
    int q = idx >> 8;
    size_t base = ((size_t)q * HEADS + h) * NS;
    float mstar = -3.0e38f;
    for (int s = 0; s < NS; ++s) mstar = fmaxf(mstar, pMS[(base + s) * 2]);
    float ssum = 0.f, acc = 0.f;
    for (int s = 0; s < NS; ++s) {
        float mi = pMS[(base + s) * 2];
        float si = pMS[(base + s) * 2 + 1];
        float w = __expf(mi - mstar);
        ssum += si * w;
        acc += pAcc[(base + s) * 32 + d] * w;
    }
    O[(size_t)q * D_MODEL + h * DH + d] = f2bf(acc / ssum);
}

// ---------------- grouped residual add + LayerNorm; rsX = Xin row stride ----------------
// fout (optional): also write the bf16-rounded result as f32 rows (CLS extraction / d_out).
__global__ void add_ln_g(const unsigned short* __restrict__ Xin, const unsigned short* __restrict__ R,
                         const float* __restrict__ w, const float* __restrict__ b,
                         unsigned short* __restrict__ Xout,
                         int M, int rows_pg, unsigned long wg, unsigned long rsX,
                         float* __restrict__ fout)
{
    int row = blockIdx.x * 4 + (threadIdx.x >> 6);
    int lane = threadIdx.x & 63;
    if (row >= M) return;
    int g = row / rows_pg;
    const float* wp = w + (size_t)g * wg;
    const float* bp = b + (size_t)g * wg;
    short4v xv = *reinterpret_cast<const short4v*>(Xin + (size_t)row * rsX + lane * 4);
    short4v rv = *reinterpret_cast<const short4v*>(R + (size_t)row * D_MODEL + lane * 4);
    float v[4];
    float sum = 0.f;
    #pragma unroll
    for (int j = 0; j < 4; ++j) {
        v[j] = bf2f((unsigned short)xv[j]) + bf2f((unsigned short)rv[j]);
        sum += v[j];
    }
    #pragma unroll
    for (int o = 32; o > 0; o >>= 1) sum += __shfl_xor(sum, o, 64);
    float mu = sum * (1.f / D_MODEL);
    float sq = 0.f;
    #pragma unroll
    for (int j = 0; j < 4; ++j) { float dd = v[j] - mu; sq += dd * dd; }
    #pragma unroll
    for (int o = 32; o > 0; o >>= 1) sq += __shfl_xor(sq, o, 64);
    float inv = rsqrtf(sq * (1.f / D_MODEL) + 1e-5f);
    short4v xb;
    #pragma unroll
    for (int j = 0; j < 4; ++j) {
        float out = (v[j] - mu) * inv * wp[lane * 4 + j] + bp[lane * 4 + j];
        xb[j] = (short)f2bf(out);
    }
    *reinterpret_cast<short4v*>(Xout + (size_t)row * D_MODEL + lane * 4) = xb;
    if (fout) {
        float4 fo;
        fo.x = bf2f((unsigned short)xb[0]);
        fo.y = bf2f((unsigned short)xb[1]);
        fo.z = bf2f((unsigned short)xb[2]);
        fo.w = bf2f((unsigned short)xb[3]);
        *reinterpret_cast<float4*>(fout + (size_t)row * D_MODEL + lane * 4) = fo;
    }
}

// ---------------- builders (bf16 Xb only) ----------------
__global__ void build_hop_seq_g(const float* __restrict__ tok, const int* __restrict__ hlist,
                                const float* __restrict__ hop_nodes,
                                unsigned short* __restrict__ Xb, int nm)
{
    int idx = blockIdx.x * blockDim.x + threadIdx.x;
    const int per = NO_HOPS * (MAX_HOP_LEN + 1) * D_MODEL;
    if (idx >= nm * per) return;
    int g = idx / per, r = idx % per;
    int d = r & 255;
    int rest = r >> 8;
    int p = rest % (MAX_HOP_LEN + 1);
    int hh = rest / (MAX_HOP_LEN + 1);
    float v;
    if (p == 0) v = hop_nodes[d];
    else {
        int node = hlist[(size_t)g * NO_HOPS * MAX_HOP_LEN + hh * MAX_HOP_LEN + p - 1];
        v = tok[(size_t)g * N_NODES * D_MODEL + (size_t)node * D_MODEL + d];
    }
    Xb[idx] = f2bf(v);
}

// pos -> inverse map: inv[g][lev][pos] = hop index; counts per level
__global__ void compute_pos_g(const int* __restrict__ hop_lev, int* __restrict__ inv,
                              int* __restrict__ counts)
{
    int g = blockIdx.x;
    const int* lev = hop_lev + (size_t)g * NO_HOPS;
    int i = threadIdx.x;
    int li = lev[i];
    int p = 0;
    for (int j = 0; j < i; ++j) p += (lev[j] == li);
    if (p < MAX_LEV_LEN)
        inv[(size_t)g * (N_LEVELS * MAX_LEV_LEN) + li * MAX_LEV_LEN + p] = i;
    if (i < N_LEVELS) {
        int c = 0;
        for (int j = 0; j < NO_HOPS; ++j) c += (lev[j] == i);
        counts[(size_t)g * N_LEVELS + i] = c;
    }
}

// merged init+scatter: build the level grid directly by gathering hop tokens via inv
__global__ void build_level_seq_g(const float* __restrict__ level_nodes,
                                  const float* __restrict__ hop_tok,
                                  const int* __restrict__ inv, const int* __restrict__ counts,
                                  unsigned short* __restrict__ Gb, int nm)
{
    int idx = blockIdx.x * blockDim.x + threadIdx.x;
    const int per = N_LEVELS * (MAX_LEV_LEN + 1) * D_MODEL;
    if (idx >= nm * per) return;
    int g = idx / per, r = idx % per;
    int d = r & 255;
    int lp = r >> 8;
    int p = lp % (MAX_LEV_LEN + 1);
    int l = lp / (MAX_LEV_LEN + 1);
    float v;
    if (p == 0) v = level_nodes[d];
    else {
        int c = counts[(size_t)g * N_LEVELS + l];
        if (p - 1 < c) {
            int hi = inv[(size_t)g * (N_LEVELS * MAX_LEV_LEN) + l * MAX_LEV_LEN + (p - 1)];
            v = hop_tok[((size_t)g * NO_HOPS + hi) * D_MODEL + d];
        } else v = 0.f;
    }
    Gb[idx] = f2bf(v);
}

__global__ void build_graph_seq_g(const float* __restrict__ graph_nodes,
                                  const float* __restrict__ lev_tok,
                                  unsigned short* __restrict__ Xb, int nm)
{
    int idx = blockIdx.x * blockDim.x + threadIdx.x;
    const int per = (N_LEVELS + 1) * D_MODEL;
    if (idx >= nm * per) return;
    int g = idx / per, r = idx % per;
    int d = r & 255;
    int p = r >> 8;
    float v = (p == 0) ? graph_nodes[d]
                       : lev_tok[(size_t)g * N_LEVELS * D_MODEL + (size_t)(p - 1) * D_MODEL + d];
    Xb[idx] = f2bf(v);
}

__global__ void build_final_seq(const float* __restrict__ masked, const float* __restrict__ hoptok,
                                const float* __restrict__ levtok, const float* __restrict__ gtok,
                                unsigned short* __restrict__ Xb)
{
    int idx = blockIdx.x * blockDim.x + threadIdx.x;
    const int total = N_FINAL * D_MODEL;
    if (idx >= total) return;
    int d = idx & 255;
    int r = idx >> 8;
    float v;
    if (r < N_MASKED) v = masked[idx];
    else {
        int t = r - N_MASKED;
        int m = t / 529;
        int w = t % 529;
        if (w < 512)      v = hoptok[((size_t)m * 512 + w) * D_MODEL + d];
        else if (w < 528) v = levtok[((size_t)m * 16 + (w - 512)) * D_MODEL + d];
        else              v = gtok[m * D_MODEL + d];
    }
    Xb[idx] = f2bf(v);
}

// ---------------- host orchestration ----------------
struct WB {
    const unsigned short *inw, *outw, *f1w, *f2w;
    const float *in_b, *out_b, *ff1_b, *ff2_b, *ln1_w, *ln1_b, *ln2_w, *ln2_b;
};

#define SZ_INW  ((size_t)3 * D_MODEL * D_MODEL)
#define SZ_OUTW ((size_t)D_MODEL * D_MODEL)
#define SZ_F1W  ((size_t)DFF * D_MODEL)
#define SZ_F2W  ((size_t)D_MODEL * DFF)
#define GS_INW  ((unsigned long)DEPTH * SZ_INW)
#define GS_INB  ((unsigned long)DEPTH * 3 * D_MODEL)
#define GS_OUTW ((unsigned long)DEPTH * SZ_OUTW)
#define GS_OUTB ((unsigned long)DEPTH * D_MODEL)
#define GS_F1W  ((unsigned long)DEPTH * SZ_F1W)
#define GS_F1B  ((unsigned long)DEPTH * DFF)
#define GS_F2W  ((unsigned long)DEPTH * SZ_F2W)
#define GS_F2B  ((unsigned long)DEPTH * D_MODEL)
#define GS_LN   ((unsigned long)DEPTH * D_MODEL)

static void launch_gemm(const unsigned short* A, unsigned long rsA, const unsigned short* Wb,
                        const float* bias, void* Yv, int M, int N, int K, int relu, int nm,
                        unsigned long xg, unsigned long wg, unsigned long bg, unsigned long yg,
                        hipStream_t stream)
{
    dim3 grid(N / 128, (M + 63) / 64, nm);
    hipLaunchKernelGGL(gemm_bb64, grid, dim3(256), 49152, stream,
                       A, Wb, bias, Yv, M, N, K, relu, rsA, xg, wg, bg, yg);
}

static void run_layer_g(unsigned short* Xb, unsigned short* QKV, unsigned short* O,
                        unsigned short* Tb, unsigned short* FF,
                        unsigned short* XC1, unsigned short* TC, unsigned short* XC2,
                        float* skAcc, float* skMS,
                        int ff_rows, int nm, int Btot, int S,
                        const int* lengths, const WB& W, int eid0, int l, int last,
                        float* cls_out, hipStream_t stream)
{
    const int Bpg = Btot / nm;
    const int Mpg = Bpg * S;
    const size_t il = (size_t)eid0 * DEPTH + l;
    // QKV: always full (K/V needed for all positions)
    launch_gemm(Xb, D_MODEL, W.inw + il * SZ_INW, W.in_b + il * 3 * D_MODEL, QKV,
                Mpg, 3 * D_MODEL, D_MODEL, 0, nm,
                (unsigned long)Mpg * D_MODEL, GS_INW, GS_INB, (unsigned long)Mpg * 3 * D_MODEL,
                stream);
    {
        int qspan = S;
        if (last && Btot == 1 && S >= 1024) qspan = N_MASKED;  // final encoder: only first 512 q rows
        int qtiles = (qspan + 63) / 64;
        if (S <= 32) {
            int blocks = (Btot * HEADS + 3) / 4;
            hipLaunchKernelGGL(attn_small, dim3(blocks), dim3(256), 0, stream,
                               QKV, lengths, O, Btot, S);
        } else if (Btot == 1 && S >= 1024) {
            dim3 grid(qtiles, HEADS, NSPLIT);
            hipLaunchKernelGGL((attn_flash<1>), grid, dim3(256), 0, stream,
                               QKV, lengths, O, Btot, S, NSPLIT, skAcc, skMS);
            int tot = qspan * HEADS * DH;
            hipLaunchKernelGGL(attn_merge, dim3((tot + 255) / 256), dim3(256), 0, stream,
                               skAcc, skMS, O, qspan, NSPLIT);
        } else {
            dim3 grid(qtiles, HEADS, Btot);
            hipLaunchKernelGGL((attn_flash<0>), grid, dim3(256), 0, stream,
                               QKV, lengths, O, Btot, S, 1, (float*)nullptr, (float*)nullptr);
        }
    }
    if (!last) {
        launch_gemm(O, D_MODEL, W.outw + il * SZ_OUTW, W.out_b + il * D_MODEL, Tb,
                    Mpg, D_MODEL, D_MODEL, 0, nm,
                    (unsigned long)Mpg * D_MODEL, GS_OUTW, GS_OUTB, (unsigned long)Mpg * D_MODEL,
                    stream);
        int Mtot = nm * Mpg;
        hipLaunchKernelGGL(add_ln_g, dim3((Mtot + 3) / 4), dim3(256), 0, stream,
                           Xb, Tb, W.ln1_w + il * D_MODEL, W.ln1_b + il * D_MODEL, Xb,
                           Mtot, Mpg, GS_LN, (unsigned long)D_MODEL, (float*)nullptr);
        for (int m0 = 0; m0 < Mpg; m0 += ff_rows) {
            int mc = (Mpg - m0 < ff_rows) ? (Mpg - m0) : ff_rows;
            launch_gemm(Xb + (size_t)m0 * D_MODEL, D_MODEL,
                        W.f1w + il * SZ_F1W, W.ff1_b + il * DFF, FF,
                        mc, DFF, D_MODEL, 1, nm,
                        (unsigned long)Mpg * D_MODEL, GS_F1W, GS_F1B, (unsigned long)mc * DFF,
                        stream);
            launch_gemm(FF, DFF, W.f2w + il * SZ_F2W, W.ff2_b + il * D_MODEL,
                        Tb + (size_t)m0 * D_MODEL,
                        mc, D_MODEL, DFF, 0, nm,
                        (unsigned long)mc * DFF, GS_F2W, GS_F2B, (unsigned long)Mpg * D_MODEL,
                        stream);
        }
        hipLaunchKernelGGL(add_ln_g, dim3((Mtot + 3) / 4), dim3(256), 0, stream,
                           Xb, Tb, W.ln2_w + il * D_MODEL, W.ln2_b + il * D_MODEL, Xb,
                           Mtot, Mpg, GS_LN, (unsigned long)D_MODEL, (float*)nullptr);
    } else {
        // Last layer: only output rows are needed downstream.
        // final encoder (S>=1024): prefix N_MASKED rows (stride 256); others: CLS row per sequence
        int Mc; unsigned long rsC;
        if (S >= 1024) { Mc = N_MASKED; rsC = (unsigned long)D_MODEL; }
        else           { Mc = Bpg;      rsC = (unsigned long)S * D_MODEL; }
        int Mtc = nm * Mc;
        launch_gemm(O, rsC, W.outw + il * SZ_OUTW, W.out_b + il * D_MODEL, TC,
                    Mc, D_MODEL, D_MODEL, 0, nm,
                    (unsigned long)Mpg * D_MODEL, GS_OUTW, GS_OUTB, (unsigned long)Mc * D_MODEL,
                    stream);
        hipLaunchKernelGGL(add_ln_g, dim3((Mtc + 3) / 4), dim3(256), 0, stream,
                           Xb, TC, W.ln1_w + il * D_MODEL, W.ln1_b + il * D_MODEL, XC1,
                           Mtc, Mc, GS_LN, rsC, (float*)nullptr);
        launch_gemm(XC1, D_MODEL, W.f1w + il * SZ_F1W, W.ff1_b + il * DFF, FF,
                    Mc, DFF, D_MODEL, 1, nm,
                    (unsigned long)Mc * D_MODEL, GS_F1W, GS_F1B, (unsigned long)Mc * DFF,
                    stream);
        launch_gemm(FF, DFF, W.f2w + il * SZ_F2W, W.ff2_b + il * D_MODEL, TC,
                    Mc, D_MODEL, DFF, 0, nm,
                    (unsigned long)Mc * DFF, GS_F2W, GS_F2B, (unsigned long)Mc * D_MODEL,
                    stream);
        // ln2 also emits the float CLS rows / final output (bit-identical to old extract path)
        hipLaunchKernelGGL(add_ln_g, dim3((Mtc + 3) / 4), dim3(256), 0, stream,
                           XC1, TC, W.ln2_w + il * D_MODEL, W.ln2_b + il * D_MODEL, XC2,
                           Mtc, Mc, GS_LN, (unsigned long)D_MODEL, cls_out);
    }
}

static void run_encoder_g(unsigned short* Xb, unsigned short* QKV, unsigned short* O,
                          unsigned short* Tb, unsigned short* FF,
                          unsigned short* XC1, unsigned short* TC, unsigned short* XC2,
                          float* skAcc, float* skMS,
                          int ff_rows, int nm, int Btot, int S,
                          const int* lengths, const WB& W, int eid0, float* cls_out,
                          hipStream_t stream)
{
    for (int l = 0; l < DEPTH; ++l)
        run_layer_g(Xb, QKV, O, Tb, FF, XC1, TC, XC2, skAcc, skMS, ff_rows, nm, Btot, S,
                    lengths, W, eid0, l, l == DEPTH - 1, cls_out, stream);
}

extern "C" void kernel_launch(void* const* d_in, const int* in_sizes, int n_in,
                              void* d_out, int out_size, void* d_ws, size_t ws_size,
                              hipStream_t stream)
{
    const float* tokens        = (const float*)d_in[0];
    const float* masked_tokens = (const float*)d_in[1];
    const float* hop_nodes     = (const float*)d_in[2];
    const float* level_nodes   = (const float*)d_in[3];
    const float* graph_nodes   = (const float*)d_in[4];
    const float* in_w  = (const float*)d_in[5];
    const float* in_b  = (const float*)d_in[6];
    const float* out_w = (const float*)d_in[7];
    const float* out_b = (const float*)d_in[8];
    const float* ff1_w = (const float*)d_in[9];
    const float* ff1_b = (const float*)d_in[10];
    const float* ff2_w = (const float*)d_in[11];
    const float* ff2_b = (const float*)d_in[12];
    const float* ln1_w = (const float*)d_in[13];
    const float* ln1_b = (const float*)d_in[14];
    const float* ln2_w = (const float*)d_in[15];
    const float* ln2_b = (const float*)d_in[16];
    const int* hop_list   = (const int*)d_in[17];
    const int* hop_lev    = (const int*)d_in[18];
    const int* hop_length = (const int*)d_in[19];

    float* ws = (float*)d_ws;
    size_t cap = ws_size / sizeof(float);
    const size_t MH = (size_t)NO_HOPS * (MAX_HOP_LEN + 1) * D_MODEL;

    const size_t N_INW  = (size_t)NLAY * SZ_INW;
    const size_t N_OUTW = (size_t)NLAY * SZ_OUTW;
    const size_t N_F1W  = (size_t)NLAY * SZ_F1W;
    const size_t N_F2W  = (size_t)NLAY * SZ_F2W;
    const size_t WBF = (N_INW + N_OUTW + N_F1W + N_F2W) / 2;
    const size_t SK_ACC = (size_t)NSPLIT * N_FINAL * HEADS * DH;
    const size_t SK_MS  = (size_t)NSPLIT * N_FINAL * HEADS * 2;
    const size_t SZC = (size_t)3 * N_MASKED * D_MODEL / 2;   // compact buf (floats)

    int NM = 3;
    {
        size_t fixed3 = 3 * MH / 2 + 3 * MH * 3 / 2 + 3 * MH / 2 + 3 * MH / 2
                      + (size_t)3 * NO_HOPS * D_MODEL + 3 * N_LEVELS * D_MODEL + 768 + 4096
                      + WBF + SK_ACC + SK_MS + 3 * SZC;
        size_t ffmin = (size_t)3 * 128 * DFF / 2;
        if (fixed3 + ffmin > cap) NM = 1;
    }

    size_t off = 0;
    auto take = [&](size_t n) { float* p = ws + off; off += (n + 7) & ~(size_t)7; return p; };
    size_t xsz = (size_t)NM * MH;
    unsigned short* Xb     = (unsigned short*)take(xsz / 2);
    unsigned short* QKV    = (unsigned short*)take(xsz * 3 / 2);
    unsigned short* O      = (unsigned short*)take(xsz / 2);
    unsigned short* Tb     = (unsigned short*)take(xsz / 2);
    float*          HOPTOK = take((size_t)3 * NO_HOPS * D_MODEL);
    float*          LEVTOK = take((size_t)3 * N_LEVELS * D_MODEL);
    float*          GTOK   = take((size_t)3 * D_MODEL);
    int*            INV    = (int*)take(2048);            // 3*512 inv + 48 counts
    int*            COUNTS = INV + 3 * (N_LEVELS * MAX_LEV_LEN);
    float*          SKACC  = take(SK_ACC);
    float*          SKMS   = take(SK_MS);
    unsigned short* XC1    = (unsigned short*)take(SZC);
    unsigned short* TC     = (unsigned short*)take(SZC);
    unsigned short* XC2    = (unsigned short*)take(SZC);
    unsigned short* WINW   = (unsigned short*)take(N_INW / 2);
    unsigned short* WOUTW  = (unsigned short*)take(N_OUTW / 2);
    unsigned short* WF1    = (unsigned short*)take(N_F1W / 2);
    unsigned short* WF2    = (unsigned short*)take(N_F2W / 2);
    unsigned short* FF     = (unsigned short*)(ws + off);
    size_t ff_ushorts = (cap > off) ? (cap - off) * 2 : 0;
    int ff_rows = (int)(ff_ushorts / ((size_t)NM * DFF));
    int max_rows = NO_HOPS * (MAX_HOP_LEN + 1);
    if (ff_rows > max_rows) ff_rows = max_rows;
    if (ff_rows > 2048) ff_rows &= ~127;
    if (ff_rows < 128) ff_rows = 128;

    {
        long n0 = (long)(N_INW / 8), n1 = (long)(N_OUTW / 8);
        long n2 = (long)(N_F1W / 8), n3 = (long)(N_F2W / 8);
        long ntot = n0 + n1 + n2 + n3;
        hipLaunchKernelGGL(cvt_w4, dim3((ntot + 255) / 256), dim3(256), 0, stream,
                           in_w, WINW, n0, out_w, WOUTW, n1, ff1_w, WF1, n2, ff2_w, WF2, n3);
    }

    WB W;
    W.inw = WINW; W.outw = WOUTW; W.f1w = WF1; W.f2w = WF2;
    W.in_b = in_b; W.out_b = out_b; W.ff1_b = ff1_b; W.ff2_b = ff2_b;
    W.ln1_w = ln1_w; W.ln1_b = ln1_b; W.ln2_w = ln2_w; W.ln2_b = ln2_b;

    for (int ms = 0; ms < 3; ms += NM) {
        const int nm = NM;
        {
            int total = nm * NO_HOPS * (MAX_HOP_LEN + 1) * D_MODEL;
            hipLaunchKernelGGL(build_hop_seq_g, dim3((total + 255) / 256), dim3(256), 0, stream,
                               tokens + (size_t)(ms + 1) * N_NODES * D_MODEL,
                               hop_list + (size_t)ms * NO_HOPS * MAX_HOP_LEN,
                               hop_nodes, Xb, nm);
        }
        run_encoder_g(Xb, QKV, O, Tb, FF, XC1, TC, XC2, SKACC, SKMS, ff_rows,
                      nm, nm * NO_HOPS, MAX_HOP_LEN + 1,
                      hop_length + (size_t)ms * NO_HOPS, W, 1 + ms,
                      HOPTOK + (size_t)ms * NO_HOPS * D_MODEL, stream);

        hipLaunchKernelGGL(compute_pos_g, dim3(nm), dim3(NO_HOPS), 0, stream,
                           hop_lev + (size_t)ms * NO_HOPS, INV, COUNTS);
        {
            int total = nm * N_LEVELS * (MAX_LEV_LEN + 1) * D_MODEL;
            hipLaunchKernelGGL(build_level_seq_g, dim3((total + 255) / 256), dim3(256), 0, stream,
                               level_nodes, HOPTOK + (size_t)ms * NO_HOPS * D_MODEL,
                               INV, COUNTS, Xb, nm);
        }
        run_encoder_g(Xb, QKV, O, Tb, FF, XC1, TC, XC2, SKACC, SKMS, ff_rows,
                      nm, nm * N_LEVELS, MAX_LEV_LEN + 1,
                      COUNTS, W, 5 + ms,
                      LEVTOK + (size_t)ms * N_LEVELS * D_MODEL, stream);

        {
            int total = nm * (N_LEVELS + 1) * D_MODEL;
            hipLaunchKernelGGL(build_graph_seq_g, dim3((total + 255) / 256), dim3(256), 0, stream,
                               graph_nodes, LEVTOK + (size_t)ms * N_LEVELS * D_MODEL, Xb, nm);
        }
        run_encoder_g(Xb, QKV, O, Tb, FF, XC1, TC, XC2, SKACC, SKMS, ff_rows,
                      nm, nm, N_LEVELS + 1,
                      nullptr, W, 9 + ms,
                      GTOK + (size_t)ms * D_MODEL, stream);
    }

    {
        int total = N_FINAL * D_MODEL;
        hipLaunchKernelGGL(build_final_seq, dim3((total + 255) / 256), dim3(256), 0, stream,
                           masked_tokens, HOPTOK, LEVTOK, GTOK, Xb);
    }
    run_encoder_g(Xb, QKV, O, Tb, FF, XC1, TC, XC2, SKACC, SKMS, ff_rows,
                  1, 1, N_FINAL, nullptr, W, 12, (float*)d_out, stream);
}

// Round 26
// 663.803 us; speedup vs baseline: 1.3417x; 1.0287x over previous
//
#include <hip/hip_runtime.h>

#define D_MODEL 256
#define HEADS 8
#define DH 32
#define DEPTH 2
#define DFF 2048
#define NO_HOPS 512
#define MAX_HOP_LEN 16
#define N_LEVELS 16
#define MAX_LEV_LEN 32
#define N_MASKED 512
#define N_NODES 8192
#define N_FINAL 2099   // 512 + 3*(512+16+1)
#define NLAY 26        // N_ENC * DEPTH
#define NSPLIT 8

typedef float f32x4 __attribute__((ext_vector_type(4)));
typedef short bf16x8 __attribute__((ext_vector_type(8)));
typedef short short4v __attribute__((ext_vector_type(4)));

#define GLOAD_LDS16(gp, lp) __builtin_amdgcn_global_load_lds( \
    (const __attribute__((address_space(1))) unsigned int*)(gp), \
    (__attribute__((address_space(3))) unsigned int*)(lp), 16, 0, 0)

__device__ __forceinline__ unsigned short f2bf(float f)
{
    unsigned int u = __builtin_bit_cast(unsigned int, f);
    unsigned int r = u + 0x7FFFu + ((u >> 16) & 1u);
    return (unsigned short)(r >> 16);
}

__device__ __forceinline__ float bf2f(unsigned short u)
{
    unsigned int x = (unsigned int)u << 16;
    return __builtin_bit_cast(float, x);
}

__device__ __forceinline__ bf16x8 cvt8(float4 a, float4 b)
{
    bf16x8 r;
    r[0] = (short)f2bf(a.x); r[1] = (short)f2bf(a.y);
    r[2] = (short)f2bf(a.z); r[3] = (short)f2bf(a.w);
    r[4] = (short)f2bf(b.x); r[5] = (short)f2bf(b.y);
    r[6] = (short)f2bf(b.z); r[7] = (short)f2bf(b.w);
    return r;
}

// ---------------- weight f32 -> bf16 conversion (4 arrays fused) ----------------
__global__ void cvt_w4(const float* __restrict__ s0, unsigned short* __restrict__ d0, long n0,
                       const float* __restrict__ s1, unsigned short* __restrict__ d1, long n1,
                       const float* __restrict__ s2, unsigned short* __restrict__ d2, long n2,
                       const float* __restrict__ s3, unsigned short* __restrict__ d3, long n3)
{
    long i = (long)blockIdx.x * blockDim.x + threadIdx.x;
    const float* s; unsigned short* d; long k;
    if (i < n0)                     { s = s0; d = d0; k = i; }
    else if (i < n0 + n1)           { s = s1; d = d1; k = i - n0; }
    else if (i < n0 + n1 + n2)      { s = s2; d = d2; k = i - n0 - n1; }
    else if (i < n0 + n1 + n2 + n3) { s = s3; d = d3; k = i - n0 - n1 - n2; }
    else return;
    const float4* sp = reinterpret_cast<const float4*>(s) + k * 2;
    *reinterpret_cast<bf16x8*>(d + k * 8) = cvt8(sp[0], sp[1]);
}

// ---------------- 64x128-tile GEMM, 512 threads (8 waves of 16x64): 48 KB, 3 blk/CU -----
// 24 waves/CU (vs 12 at 256 thr) to hide the 2-phase stage/drain latency via TLP.
// Per-output K-accumulation order identical to the 256-thread version (bitwise-same C).
// rsA = element stride between consecutive A rows (rsA == K for dense; S*256 for CLS rows).
__global__ __launch_bounds__(512) void gemm_bb64(
    const unsigned short* __restrict__ A, const unsigned short* __restrict__ Wb,
    const float* __restrict__ bias, void* __restrict__ Yv,
    int M, int N, int K, int relu,
    unsigned long rsA, unsigned long xg, unsigned long wg, unsigned long bg, unsigned long yg)
{
    extern __shared__ unsigned short sh[];     // 24576 shorts = 48 KB
    const int grp = blockIdx.z;
    const int t = threadIdx.x;
    const int lane = t & 63, wid = t >> 6;     // 8 waves
    const int wr = wid & 3, wc = wid >> 2;     // wave = 16 rows x 64 cols
    const int rowbase = blockIdx.y * 64;
    const int colbase = blockIdx.x * 128;
    const unsigned short* Abase = A + (size_t)grp * xg;
    const unsigned short* Wbase = Wb + (size_t)grp * wg;

    // A staging: 64 rows x 64 k = 512 chunks -> 1 per thread
    const unsigned short* gA; unsigned short* lA;
    {
        int sr = t >> 3, p = t & 7;
        int lc = p ^ (sr & 7);
        int ar = rowbase + sr; if (ar >= M) ar = M - 1;
        gA = Abase + (size_t)ar * rsA + lc * 8;
        lA = sh + (t & ~63) * 8;
    }
    // B staging: 128 cols x 64 k = 1024 chunks -> 2 per thread
    const unsigned short* gB[2]; unsigned short* lB[2];
    #pragma unroll
    for (int j = 0; j < 2; ++j) {
        int c = j * 512 + t;
        int sr = c >> 3, p = c & 7;
        int lc = p ^ (sr & 7);
        gB[j] = Wbase + (size_t)(colbase + sr) * K + lc * 8;
        lB[j] = sh + 8192 + (j * 512 + (t & ~63)) * 8;
    }

    f32x4 acc[4];
    #pragma unroll
    for (int n = 0; n < 4; ++n)
        acc[n] = (f32x4){0.f, 0.f, 0.f, 0.f};

    const int g = lane >> 4, rr = lane & 15;
    const int nt = K >> 6;

    GLOAD_LDS16(gA, lA);
    #pragma unroll
    for (int j = 0; j < 2; ++j) GLOAD_LDS16(gB[j], lB[j]);

    int buf = 0;
    for (int tt = 0; tt < nt; ++tt) {
        if (tt + 1 < nt) {
            const int k1 = (tt + 1) << 6;
            const int oa = (buf ^ 1) * 4096;
            const int ob = (buf ^ 1) * 8192;
            GLOAD_LDS16(gA + k1, lA + oa);
            #pragma unroll
            for (int j = 0; j < 2; ++j) GLOAD_LDS16(gB[j] + k1, lB[j] + ob);
            asm volatile("s_waitcnt vmcnt(3)\n\ts_barrier" ::: "memory");
        } else {
            asm volatile("s_waitcnt vmcnt(0)\n\ts_barrier" ::: "memory");
        }
        const unsigned short* Ab = sh + buf * 4096;
        const unsigned short* Bb = sh + 8192 + buf * 8192;
        #pragma unroll
        for (int ks = 0; ks < 2; ++ks) {
            bf16x8 af, bfr[4];
            {
                int row = wr * 16 + rr;
                int lc = ks * 4 + g;
                af = *reinterpret_cast<const bf16x8*>(&Ab[row * 64 + ((lc ^ (row & 7)) * 8)]);
            }
            #pragma unroll
            for (int n = 0; n < 4; ++n) {
                int col = wc * 64 + n * 16 + rr;
                int lc = ks * 4 + g;
                bfr[n] = *reinterpret_cast<const bf16x8*>(&Bb[col * 64 + ((lc ^ (col & 7)) * 8)]);
            }
            #pragma unroll
            for (int n = 0; n < 4; ++n)
                acc[n] = __builtin_amdgcn_mfma_f32_16x16x32_bf16(af, bfr[n], acc[n], 0, 0, 0);
        }
        asm volatile("s_barrier" ::: "memory");
        buf ^= 1;
    }

    const int rg = lane >> 4;
    const float* bp = bias + (size_t)grp * bg;
    #pragma unroll
    for (int n = 0; n < 4; ++n) {
        int coll = wc * 64 + n * 16 + rr;
        float bv = bp[colbase + coll];
        #pragma unroll
        for (int i = 0; i < 4; ++i) {
            int rowl = wr * 16 + rg * 4 + i;
            float v = acc[n][i] + bv;
            if (relu) v = fmaxf(v, 0.f);
            sh[rowl * 128 + coll] = f2bf(v);
        }
    }
    __syncthreads();
    unsigned short* Y = (unsigned short*)Yv + (size_t)grp * yg;
    int row = t >> 3, seg = t & 7;
    int grow = rowbase + row;
    if (grow < M) {
        const unsigned short* s = &sh[row * 128 + seg * 16];
        unsigned short* d = Y + (size_t)grow * N + colbase + seg * 16;
        #pragma unroll
        for (int j = 0; j < 2; ++j)
            *reinterpret_cast<bf16x8*>(d + j * 8) = *reinterpret_cast<const bf16x8*>(s + j * 8);
    }
}

// ---------------- small-S attention (S <= 32): one wave per (b,h), 4 per block ----------
__global__ __launch_bounds__(256) void attn_small(
    const unsigned short* __restrict__ QKV, const int* __restrict__ lengths,
    unsigned short* __restrict__ O, int B, int S)
{
    __shared__ __align__(16) unsigned short Ksm[4][32][40];
    __shared__ __align__(16) unsigned short Vsm[4][32][40];
    __shared__ __align__(16) unsigned short Psm[4][32][40];
    const int t = threadIdx.x;
    const int w = t >> 6, lane = t & 63;
    const int l15 = lane & 15, g = lane >> 4;
    int bh = blockIdx.x * 4 + w;
    const int BH = B * HEADS;
    if (bh >= BH) bh = BH - 1;
    const int b = bh >> 3, h = bh & 7;
    const unsigned short* base = QKV + (size_t)b * S * (3 * D_MODEL);
    int len_eff = S - 1;
    if (lengths) { int L = lengths[b]; if (L < len_eff) len_eff = L; }

    {
        int key = lane >> 1, hf = lane & 1;
        int kg = key < S ? key : S - 1;
        const unsigned short* kp = base + (size_t)kg * (3 * D_MODEL) + D_MODEL + h * DH + hf * 16;
        bf16x8 k0 = *reinterpret_cast<const bf16x8*>(kp);
        bf16x8 k1 = *reinterpret_cast<const bf16x8*>(kp + 8);
        *reinterpret_cast<bf16x8*>(&Ksm[w][key][hf * 16]) = k0;
        *reinterpret_cast<bf16x8*>(&Ksm[w][key][hf * 16 + 8]) = k1;
        const unsigned short* vp = kp + D_MODEL;
        bf16x8 v0 = *reinterpret_cast<const bf16x8*>(vp);
        bf16x8 v1 = *reinterpret_cast<const bf16x8*>(vp + 8);
        #pragma unroll
        for (int i = 0; i < 8; ++i) {
            Vsm[w][hf * 16 + i][key]     = (unsigned short)v0[i];
            Vsm[w][hf * 16 + 8 + i][key] = (unsigned short)v1[i];
        }
    }
    bf16x8 qa[2];
    #pragma unroll
    for (int qf = 0; qf < 2; ++qf) {
        int q = qf * 16 + l15; if (q > S - 1) q = S - 1;
        qa[qf] = *reinterpret_cast<const bf16x8*>(base + (size_t)q * (3 * D_MODEL) + h * DH + g * 8);
    }
    __syncthreads();

    const float scale = 0.17677669529663687f;
    const f32x4 zero = (f32x4){0.f,0.f,0.f,0.f};
    f32x4 sc[2][2];
    #pragma unroll
    for (int kf = 0; kf < 2; ++kf) {
        bf16x8 kb = *reinterpret_cast<const bf16x8*>(&Ksm[w][kf * 16 + l15][g * 8]);
        #pragma unroll
        for (int qf = 0; qf < 2; ++qf)
            sc[qf][kf] = __builtin_amdgcn_mfma_f32_16x16x32_bf16(qa[qf], kb, zero, 0, 0, 0);
    }
    float rsum[2][4];
    #pragma unroll
    for (int qf = 0; qf < 2; ++qf) {
        #pragma unroll
        for (int kf = 0; kf < 2; ++kf) {
            if (kf * 16 + l15 > len_eff) sc[qf][kf] = (f32x4){-1e9f,-1e9f,-1e9f,-1e9f};
            else sc[qf][kf] *= scale;
        }
        #pragma unroll
        for (int r = 0; r < 4; ++r) {
            float mx = fmaxf(sc[qf][0][r], sc[qf][1][r]);
            mx = fmaxf(mx, __shfl_xor(mx, 1, 64));
            mx = fmaxf(mx, __shfl_xor(mx, 2, 64));
            mx = fmaxf(mx, __shfl_xor(mx, 4, 64));
            mx = fmaxf(mx, __shfl_xor(mx, 8, 64));
            float s0 = __expf(sc[qf][0][r] - mx);
            float s1 = __expf(sc[qf][1][r] - mx);
            sc[qf][0][r] = s0;
            sc[qf][1][r] = s1;
            float ss = s0 + s1;
            ss += __shfl_xor(ss, 1, 64);
            ss += __shfl_xor(ss, 2, 64);
            ss += __shfl_xor(ss, 4, 64);
            ss += __shfl_xor(ss, 8, 64);
            rsum[qf][r] = ss;
        }
    }
    #pragma unroll
    for (int qf = 0; qf < 2; ++qf)
        #pragma unroll
        for (int kf = 0; kf < 2; ++kf)
            #pragma unroll
            for (int r = 0; r < 4; ++r)
                Psm[w][qf * 16 + g * 4 + r][kf * 16 + l15] = f2bf(sc[qf][kf][r]);
    __syncthreads();

    f32x4 o[2][2];
    #pragma unroll
    for (int df = 0; df < 2; ++df) {
        bf16x8 vb = *reinterpret_cast<const bf16x8*>(&Vsm[w][df * 16 + l15][g * 8]);
        #pragma unroll
        for (int qf = 0; qf < 2; ++qf) {
            bf16x8 pa = *reinterpret_cast<const bf16x8*>(&Psm[w][qf * 16 + l15][g * 8]);
            o[qf][df] = __builtin_amdgcn_mfma_f32_16x16x32_bf16(pa, vb, zero, 0, 0, 0);
        }
    }
    #pragma unroll
    for (int qf = 0; qf < 2; ++qf)
        #pragma unroll
        for (int r = 0; r < 4; ++r) {
            int q = qf * 16 + g * 4 + r;
            if (q < S) {
                float inv = 1.f / rsum[qf][r];
                #pragma unroll
                for (int df = 0; df < 2; ++df)
                    O[((size_t)b * S + q) * D_MODEL + h * DH + df * 16 + l15] = f2bf(o[qf][df][r] * inv);
            }
        }
}

// ---------------- MFMA flash attention; SPLIT=1: K-split partials (B must be 1) ----------
template<int SPLIT>
__global__ __launch_bounds__(256) void attn_flash(
    const unsigned short* __restrict__ QKV, const int* __restrict__ lengths,
    unsigned short* __restrict__ O, int B, int S,
    int NSv, float* __restrict__ pAcc, float* __restrict__ pMS)
{
    __shared__ __align__(16) unsigned short Kt[64][32];
    __shared__ __align__(16) unsigned short Vt[32][64];
    __shared__ __align__(16) unsigned short Pw[4][16][64];

    const int t = threadIdx.x;
    const int lane = t & 63, wid = t >> 6;
    const int l15 = lane & 15, g = lane >> 4;
    const int b = SPLIT ? 0 : blockIdx.z;
    const int sp = SPLIT ? blockIdx.z : 0;
    const int h = blockIdx.y;
    const int qb = blockIdx.x * 64 + wid * 16;
    const unsigned short* base = QKV + (size_t)b * S * (3 * D_MODEL);

    int len_eff = S - 1;
    if (lengths) { int L = lengths[b]; if (L < len_eff) len_eff = L; }

    const float scale = 0.17677669529663687f;
    int qrow = qb + l15; if (qrow > S - 1) qrow = S - 1;
    bf16x8 qa = *reinterpret_cast<const bf16x8*>(base + (size_t)qrow * (3 * D_MODEL) + h * DH + g * 8);

    float m[4], sum[4];
    f32x4 o[2];
    #pragma unroll
    for (int r = 0; r < 4; ++r) { m[r] = -3.0e38f; sum[r] = 0.f; }
    o[0] = (f32x4){0.f,0.f,0.f,0.f};
    o[1] = (f32x4){0.f,0.f,0.f,0.f};

    const int kl = t >> 2, cg = t & 3;
    const int ntiles_all = (S + 63) >> 6;
    int tstart = 0, tend = ntiles_all;
    if (SPLIT) {
        int chunkT = (ntiles_all + NSv - 1) / NSv;
        tstart = sp * chunkT;
        tend = tstart + chunkT;
        if (tend > ntiles_all) tend = ntiles_all;
    }

    for (int tt = tstart; tt < tend; ++tt) {
        const int kbase = tt * 64;
        {
            int key = kbase + kl; if (key > S - 1) key = S - 1;
            const unsigned short* kp = base + (size_t)key * (3 * D_MODEL) + D_MODEL + h * DH + cg * 8;
            *reinterpret_cast<bf16x8*>(&Kt[kl][cg * 8]) = *reinterpret_cast<const bf16x8*>(kp);
            bf16x8 vv = *reinterpret_cast<const bf16x8*>(kp + D_MODEL);
            #pragma unroll
            for (int i = 0; i < 8; ++i) {
                int d = cg * 8 + i;
                int c = ((kl >> 3) ^ (d & 7)) * 8 + (kl & 7);
                Vt[d][c] = (unsigned short)vv[i];
            }
        }
        __syncthreads();

        f32x4 sc[4];
        const f32x4 zero = (f32x4){0.f,0.f,0.f,0.f};
        #pragma unroll
        for (int f = 0; f < 4; ++f) {
            bf16x8 kf = *reinterpret_cast<const bf16x8*>(&Kt[f * 16 + l15][g * 8]);
            sc[f] = __builtin_amdgcn_mfma_f32_16x16x32_bf16(qa, kf, zero, 0, 0, 0);
            sc[f] *= scale;
        }
        #pragma unroll
        for (int f = 0; f < 4; ++f) {
            if (kbase + f * 16 + l15 > len_eff)
                sc[f] = (f32x4){-1e9f,-1e9f,-1e9f,-1e9f};
        }
        float cr[4];
        #pragma unroll
        for (int r = 0; r < 4; ++r) {
            float mx = fmaxf(fmaxf(sc[0][r], sc[1][r]), fmaxf(sc[2][r], sc[3][r]));
            mx = fmaxf(mx, __shfl_xor(mx, 1, 64));
            mx = fmaxf(mx, __shfl_xor(mx, 2, 64));
            mx = fmaxf(mx, __shfl_xor(mx, 4, 64));
            mx = fmaxf(mx, __shfl_xor(mx, 8, 64));
            float nm = fmaxf(m[r], mx);
            cr[r] = __expf(m[r] - nm);
            m[r] = nm;
            float ssum = 0.f;
            #pragma unroll
            for (int f = 0; f < 4; ++f) {
                float e = __expf(sc[f][r] - nm);
                sc[f][r] = e;
                ssum += e;
            }
            ssum += __shfl_xor(ssum, 1, 64);
            ssum += __shfl_xor(ssum, 2, 64);
            ssum += __shfl_xor(ssum, 4, 64);
            ssum += __shfl_xor(ssum, 8, 64);
            sum[r] = sum[r] * cr[r] + ssum;
            o[0][r] *= cr[r];
            o[1][r] *= cr[r];
        }
        #pragma unroll
        for (int f = 0; f < 4; ++f) {
            int chunk = f * 2 + (l15 >> 3);
            #pragma unroll
            for (int r = 0; r < 4; ++r) {
                int row = g * 4 + r;
                Pw[wid][row][(chunk ^ (row & 7)) * 8 + (l15 & 7)] = f2bf(sc[f][r]);
            }
        }
        #pragma unroll
        for (int s = 0; s < 2; ++s) {
            bf16x8 pa = *reinterpret_cast<const bf16x8*>(
                &Pw[wid][l15][((s * 4 + g) ^ (l15 & 7)) * 8]);
            #pragma unroll
            for (int jf = 0; jf < 2; ++jf) {
                int d = jf * 16 + l15;
                bf16x8 vb = *reinterpret_cast<const bf16x8*>(
                    &Vt[d][((s * 4 + g) ^ (d & 7)) * 8]);
                o[jf] = __builtin_amdgcn_mfma_f32_16x16x32_bf16(pa, vb, o[jf], 0, 0, 0);
            }
        }
        __syncthreads();
    }

    if (SPLIT) {
        #pragma unroll
        for (int r = 0; r < 4; ++r) {
            int qout = qb + g * 4 + r;
            if (qout < S) {
                size_t pb = ((size_t)qout * HEADS + h) * NSv + sp;
                pAcc[pb * 32 + l15]      = o[0][r];
                pAcc[pb * 32 + 16 + l15] = o[1][r];
                if (l15 == 0) { pMS[pb * 2] = m[r]; pMS[pb * 2 + 1] = sum[r]; }
            }
        }
    } else {
        #pragma unroll
        for (int r = 0; r < 4; ++r) {
            float inv = 1.f / sum[r];
            int qout = qb + g * 4 + r;
            if (qout < S) {
                #pragma unroll
                for (int jf = 0; jf < 2; ++jf)
                    O[((size_t)b * S + qout) * D_MODEL + h * DH + jf * 16 + l15] = f2bf(o[jf][r] * inv);
            }
        }
    }
}

// ---------------- split-K merge ----------------
__global__ void attn_merge(const float* __restrict__ pAcc, const float* __restrict__ pMS,
                           unsigned short* __restrict__ O, int S, int NS)
{
    int idx = blockIdx.x * blockDim.x + threadIdx.x;
    if (idx >= S * HEADS * DH) return;
    int d = idx & 31;
    int h = (idx >> 5) & 7;
    int q = idx >> 8;
    size_t base = ((size_t)q * HEADS + h) * NS;
    float mstar = -3.0e38f;
    for (int s = 0; s < NS; ++s) mstar = fmaxf(mstar, pMS[(base + s) * 2]);
    float ssum = 0.f, acc = 0.f;
    for (int s = 0; s < NS; ++s) {
        float mi = pMS[(base + s) * 2];
        float si = pMS[(base + s) * 2 + 1];
        float w = __expf(mi - mstar);
        ssum += si * w;
        acc += pAcc[(base + s) * 32 + d] * w;
    }
    O[(size_t)q * D_MODEL + h * DH + d] = f2bf(acc / ssum);
}

// ---------------- grouped residual add + LayerNorm; rsX = Xin row stride ----------------
// fout (optional): also write the bf16-rounded result as f32 rows (CLS extraction / d_out).
__global__ void add_ln_g(const unsigned short* __restrict__ Xin, const unsigned short* __restrict__ R,
                         const float* __restrict__ w, const float* __restrict__ b,
                         unsigned short* __restrict__ Xout,
                         int M, int rows_pg, unsigned long wg, unsigned long rsX,
                         float* __restrict__ fout)
{
    int row = blockIdx.x * 4 + (threadIdx.x >> 6);
    int lane = threadIdx.x & 63;
    if (row >= M) return;
    int g = row / rows_pg;
    const float* wp = w + (size_t)g * wg;
    const float* bp = b + (size_t)g * wg;
    short4v xv = *reinterpret_cast<const short4v*>(Xin + (size_t)row * rsX + lane * 4);
    short4v rv = *reinterpret_cast<const short4v*>(R + (size_t)row * D_MODEL + lane * 4);
    float v[4];
    float sum = 0.f;
    #pragma unroll
    for (int j = 0; j < 4; ++j) {
        v[j] = bf2f((unsigned short)xv[j]) + bf2f((unsigned short)rv[j]);
        sum += v[j];
    }
    #pragma unroll
    for (int o = 32; o > 0; o >>= 1) sum += __shfl_xor(sum, o, 64);
    float mu = sum * (1.f / D_MODEL);
    float sq = 0.f;
    #pragma unroll
    for (int j = 0; j < 4; ++j) { float dd = v[j] - mu; sq += dd * dd; }
    #pragma unroll
    for (int o = 32; o > 0; o >>= 1) sq += __shfl_xor(sq, o, 64);
    float inv = rsqrtf(sq * (1.f / D_MODEL) + 1e-5f);
    short4v xb;
    #pragma unroll
    for (int j = 0; j < 4; ++j) {
        float out = (v[j] - mu) * inv * wp[lane * 4 + j] + bp[lane * 4 + j];
        xb[j] = (short)f2bf(out);
    }
    *reinterpret_cast<short4v*>(Xout + (size_t)row * D_MODEL + lane * 4) = xb;
    if (fout) {
        float4 fo;
        fo.x = bf2f((unsigned short)xb[0]);
        fo.y = bf2f((unsigned short)xb[1]);
        fo.z = bf2f((unsigned short)xb[2]);
        fo.w = bf2f((unsigned short)xb[3]);
        *reinterpret_cast<float4*>(fout + (size_t)row * D_MODEL + lane * 4) = fo;
    }
}

// ---------------- builders (bf16 Xb only) ----------------
__global__ void build_hop_seq_g(const float* __restrict__ tok, const int* __restrict__ hlist,
                                const float* __restrict__ hop_nodes,
                                unsigned short* __restrict__ Xb, int nm)
{
    int idx = blockIdx.x * blockDim.x + threadIdx.x;
    const int per = NO_HOPS * (MAX_HOP_LEN + 1) * D_MODEL;
    if (idx >= nm * per) return;
    int g = idx / per, r = idx % per;
    int d = r & 255;
    int rest = r >> 8;
    int p = rest % (MAX_HOP_LEN + 1);
    int hh = rest / (MAX_HOP_LEN + 1);
    float v;
    if (p == 0) v = hop_nodes[d];
    else {
        int node = hlist[(size_t)g * NO_HOPS * MAX_HOP_LEN + hh * MAX_HOP_LEN + p - 1];
        v = tok[(size_t)g * N_NODES * D_MODEL + (size_t)node * D_MODEL + d];
    }
    Xb[idx] = f2bf(v);
}

// pos -> inverse map: inv[g][lev][pos] = hop index; counts per level
__global__ void compute_pos_g(const int* __restrict__ hop_lev, int* __restrict__ inv,
                              int* __restrict__ counts)
{
    int g = blockIdx.x;
    const int* lev = hop_lev + (size_t)g * NO_HOPS;
    int i = threadIdx.x;
    int li = lev[i];
    int p = 0;
    for (int j = 0; j < i; ++j) p += (lev[j] == li);
    if (p < MAX_LEV_LEN)
        inv[(size_t)g * (N_LEVELS * MAX_LEV_LEN) + li * MAX_LEV_LEN + p] = i;
    if (i < N_LEVELS) {
        int c = 0;
        for (int j = 0; j < NO_HOPS; ++j) c += (lev[j] == i);
        counts[(size_t)g * N_LEVELS + i] = c;
    }
}

// merged init+scatter: build the level grid directly by gathering hop tokens via inv
__global__ void build_level_seq_g(const float* __restrict__ level_nodes,
                                  const float* __restrict__ hop_tok,
                                  const int* __restrict__ inv, const int* __restrict__ counts,
                                  unsigned short* __restrict__ Gb, int nm)
{
    int idx = blockIdx.x * blockDim.x + threadIdx.x;
    const int per = N_LEVELS * (MAX_LEV_LEN + 1) * D_MODEL;
    if (idx >= nm * per) return;
    int g = idx / per, r = idx % per;
    int d = r & 255;
    int lp = r >> 8;
    int p = lp % (MAX_LEV_LEN + 1);
    int l = lp / (MAX_LEV_LEN + 1);
    float v;
    if (p == 0) v = level_nodes[d];
    else {
        int c = counts[(size_t)g * N_LEVELS + l];
        if (p - 1 < c) {
            int hi = inv[(size_t)g * (N_LEVELS * MAX_LEV_LEN) + l * MAX_LEV_LEN + (p - 1)];
            v = hop_tok[((size_t)g * NO_HOPS + hi) * D_MODEL + d];
        } else v = 0.f;
    }
    Gb[idx] = f2bf(v);
}

__global__ void build_graph_seq_g(const float* __restrict__ graph_nodes,
                                  const float* __restrict__ lev_tok,
                                  unsigned short* __restrict__ Xb, int nm)
{
    int idx = blockIdx.x * blockDim.x + threadIdx.x;
    const int per = (N_LEVELS + 1) * D_MODEL;
    if (idx >= nm * per) return;
    int g = idx / per, r = idx % per;
    int d = r & 255;
    int p = r >> 8;
    float v = (p == 0) ? graph_nodes[d]
                       : lev_tok[(size_t)g * N_LEVELS * D_MODEL + (size_t)(p - 1) * D_MODEL + d];
    Xb[idx] = f2bf(v);
}

__global__ void build_final_seq(const float* __restrict__ masked, const float* __restrict__ hoptok,
                                const float* __restrict__ levtok, const float* __restrict__ gtok,
                                unsigned short* __restrict__ Xb)
{
    int idx = blockIdx.x * blockDim.x + threadIdx.x;
    const int total = N_FINAL * D_MODEL;
    if (idx >= total) return;
    int d = idx & 255;
    int r = idx >> 8;
    float v;
    if (r < N_MASKED) v = masked[idx];
    else {
        int t = r - N_MASKED;
        int m = t / 529;
        int w = t % 529;
        if (w < 512)      v = hoptok[((size_t)m * 512 + w) * D_MODEL + d];
        else if (w < 528) v = levtok[((size_t)m * 16 + (w - 512)) * D_MODEL + d];
        else              v = gtok[m * D_MODEL + d];
    }
    Xb[idx] = f2bf(v);
}

// ---------------- host orchestration ----------------
struct WB {
    const unsigned short *inw, *outw, *f1w, *f2w;
    const float *in_b, *out_b, *ff1_b, *ff2_b, *ln1_w, *ln1_b, *ln2_w, *ln2_b;
};

#define SZ_INW  ((size_t)3 * D_MODEL * D_MODEL)
#define SZ_OUTW ((size_t)D_MODEL * D_MODEL)
#define SZ_F1W  ((size_t)DFF * D_MODEL)
#define SZ_F2W  ((size_t)D_MODEL * DFF)
#define GS_INW  ((unsigned long)DEPTH * SZ_INW)
#define GS_INB  ((unsigned long)DEPTH * 3 * D_MODEL)
#define GS_OUTW ((unsigned long)DEPTH * SZ_OUTW)
#define GS_OUTB ((unsigned long)DEPTH * D_MODEL)
#define GS_F1W  ((unsigned long)DEPTH * SZ_F1W)
#define GS_F1B  ((unsigned long)DEPTH * DFF)
#define GS_F2W  ((unsigned long)DEPTH * SZ_F2W)
#define GS_F2B  ((unsigned long)DEPTH * D_MODEL)
#define GS_LN   ((unsigned long)DEPTH * D_MODEL)

static void launch_gemm(const unsigned short* A, unsigned long rsA, const unsigned short* Wb,
                        const float* bias, void* Yv, int M, int N, int K, int relu, int nm,
                        unsigned long xg, unsigned long wg, unsigned long bg, unsigned long yg,
                        hipStream_t stream)
{
    dim3 grid(N / 128, (M + 63) / 64, nm);
    hipLaunchKernelGGL(gemm_bb64, grid, dim3(512), 49152, stream,
                       A, Wb, bias, Yv, M, N, K, relu, rsA, xg, wg, bg, yg);
}

static void run_layer_g(unsigned short* Xb, unsigned short* QKV, unsigned short* O,
                        unsigned short* Tb, unsigned short* FF,
                        unsigned short* XC1, unsigned short* TC, unsigned short* XC2,
                        float* skAcc, float* skMS,
                        int ff_rows, int nm, int Btot, int S,
                        const int* lengths, const WB& W, int eid0, int l, int last,
                        float* cls_out, hipStream_t stream)
{
    const int Bpg = Btot / nm;
    const int Mpg = Bpg * S;
    const size_t il = (size_t)eid0 * DEPTH + l;
    // QKV: always full (K/V needed for all positions)
    launch_gemm(Xb, D_MODEL, W.inw + il * SZ_INW, W.in_b + il * 3 * D_MODEL, QKV,
                Mpg, 3 * D_MODEL, D_MODEL, 0, nm,
                (unsigned long)Mpg * D_MODEL, GS_INW, GS_INB, (unsigned long)Mpg * 3 * D_MODEL,
                stream);
    {
        int qspan = S;
        if (last && Btot == 1 && S >= 1024) qspan = N_MASKED;  // final encoder: only first 512 q rows
        int qtiles = (qspan + 63) / 64;
        if (S <= 32) {
            int blocks = (Btot * HEADS + 3) / 4;
            hipLaunchKernelGGL(attn_small, dim3(blocks), dim3(256), 0, stream,
                               QKV, lengths, O, Btot, S);
        } else if (Btot == 1 && S >= 1024) {
            dim3 grid(qtiles, HEADS, NSPLIT);
            hipLaunchKernelGGL((attn_flash<1>), grid, dim3(256), 0, stream,
                               QKV, lengths, O, Btot, S, NSPLIT, skAcc, skMS);
            int tot = qspan * HEADS * DH;
            hipLaunchKernelGGL(attn_merge, dim3((tot + 255) / 256), dim3(256), 0, stream,
                               skAcc, skMS, O, qspan, NSPLIT);
        } else {
            dim3 grid(qtiles, HEADS, Btot);
            hipLaunchKernelGGL((attn_flash<0>), grid, dim3(256), 0, stream,
                               QKV, lengths, O, Btot, S, 1, (float*)nullptr, (float*)nullptr);
        }
    }
    if (!last) {
        launch_gemm(O, D_MODEL, W.outw + il * SZ_OUTW, W.out_b + il * D_MODEL, Tb,
                    Mpg, D_MODEL, D_MODEL, 0, nm,
                    (unsigned long)Mpg * D_MODEL, GS_OUTW, GS_OUTB, (unsigned long)Mpg * D_MODEL,
                    stream);
        int Mtot = nm * Mpg;
        hipLaunchKernelGGL(add_ln_g, dim3((Mtot + 3) / 4), dim3(256), 0, stream,
                           Xb, Tb, W.ln1_w + il * D_MODEL, W.ln1_b + il * D_MODEL, Xb,
                           Mtot, Mpg, GS_LN, (unsigned long)D_MODEL, (float*)nullptr);
        for (int m0 = 0; m0 < Mpg; m0 += ff_rows) {
            int mc = (Mpg - m0 < ff_rows) ? (Mpg - m0) : ff_rows;
            launch_gemm(Xb + (size_t)m0 * D_MODEL, D_MODEL,
                        W.f1w + il * SZ_F1W, W.ff1_b + il * DFF, FF,
                        mc, DFF, D_MODEL, 1, nm,
                        (unsigned long)Mpg * D_MODEL, GS_F1W, GS_F1B, (unsigned long)mc * DFF,
                        stream);
            launch_gemm(FF, DFF, W.f2w + il * SZ_F2W, W.ff2_b + il * D_MODEL,
                        Tb + (size_t)m0 * D_MODEL,
                        mc, D_MODEL, DFF, 0, nm,
                        (unsigned long)mc * DFF, GS_F2W, GS_F2B, (unsigned long)Mpg * D_MODEL,
                        stream);
        }
        hipLaunchKernelGGL(add_ln_g, dim3((Mtot + 3) / 4), dim3(256), 0, stream,
                           Xb, Tb, W.ln2_w + il * D_MODEL, W.ln2_b + il * D_MODEL, Xb,
                           Mtot, Mpg, GS_LN, (unsigned long)D_MODEL, (float*)nullptr);
    } else {
        // Last layer: only output rows are needed downstream.
        // final encoder (S>=1024): prefix N_MASKED rows (stride 256); others: CLS row per sequence
        int Mc; unsigned long rsC;
        if (S >= 1024) { Mc = N_MASKED; rsC = (unsigned long)D_MODEL; }
        else           { Mc = Bpg;      rsC = (unsigned long)S * D_MODEL; }
        int Mtc = nm * Mc;
        launch_gemm(O, rsC, W.outw + il * SZ_OUTW, W.out_b + il * D_MODEL, TC,
                    Mc, D_MODEL, D_MODEL, 0, nm,
                    (unsigned long)Mpg * D_MODEL, GS_OUTW, GS_OUTB, (unsigned long)Mc * D_MODEL,
                    stream);
        hipLaunchKernelGGL(add_ln_g, dim3((Mtc + 3) / 4), dim3(256), 0, stream,
                           Xb, TC, W.ln1_w + il * D_MODEL, W.ln1_b + il * D_MODEL, XC1,
                           Mtc, Mc, GS_LN, rsC, (float*)nullptr);
        launch_gemm(XC1, D_MODEL, W.f1w + il * SZ_F1W, W.ff1_b + il * DFF, FF,
                    Mc, DFF, D_MODEL, 1, nm,
                    (unsigned long)Mc * D_MODEL, GS_F1W, GS_F1B, (unsigned long)Mc * DFF,
                    stream);
        launch_gemm(FF, DFF, W.f2w + il * SZ_F2W, W.ff2_b + il * D_MODEL, TC,
                    Mc, D_MODEL, DFF, 0, nm,
                    (unsigned long)Mc * DFF, GS_F2W, GS_F2B, (unsigned long)Mc * D_MODEL,
                    stream);
        // ln2 also emits the float CLS rows / final output (bit-identical to old extract path)
        hipLaunchKernelGGL(add_ln_g, dim3((Mtc + 3) / 4), dim3(256), 0, stream,
                           XC1, TC, W.ln2_w + il * D_MODEL, W.ln2_b + il * D_MODEL, XC2,
                           Mtc, Mc, GS_LN, (unsigned long)D_MODEL, cls_out);
    }
}

static void run_encoder_g(unsigned short* Xb, unsigned short* QKV, unsigned short* O,
                          unsigned short* Tb, unsigned short* FF,
                          unsigned short* XC1, unsigned short* TC, unsigned short* XC2,
                          float* skAcc, float* skMS,
                          int ff_rows, int nm, int Btot, int S,
                          const int* lengths, const WB& W, int eid0, float* cls_out,
                          hipStream_t stream)
{
    for (int l = 0; l < DEPTH; ++l)
        run_layer_g(Xb, QKV, O, Tb, FF, XC1, TC, XC2, skAcc, skMS, ff_rows, nm, Btot, S,
                    lengths, W, eid0, l, l == DEPTH - 1, cls_out, stream);
}

extern "C" void kernel_launch(void* const* d_in, const int* in_sizes, int n_in,
                              void* d_out, int out_size, void* d_ws, size_t ws_size,
                              hipStream_t stream)
{
    const float* tokens        = (const float*)d_in[0];
    const float* masked_tokens = (const float*)d_in[1];
    const float* hop_nodes     = (const float*)d_in[2];
    const float* level_nodes   = (const float*)d_in[3];
    const float* graph_nodes   = (const float*)d_in[4];
    const float* in_w  = (const float*)d_in[5];
    const float* in_b  = (const float*)d_in[6];
    const float* out_w = (const float*)d_in[7];
    const float* out_b = (const float*)d_in[8];
    const float* ff1_w = (const float*)d_in[9];
    const float* ff1_b = (const float*)d_in[10];
    const float* ff2_w = (const float*)d_in[11];
    const float* ff2_b = (const float*)d_in[12];
    const float* ln1_w = (const float*)d_in[13];
    const float* ln1_b = (const float*)d_in[14];
    const float* ln2_w = (const float*)d_in[15];
    const float* ln2_b = (const float*)d_in[16];
    const int* hop_list   = (const int*)d_in[17];
    const int* hop_lev    = (const int*)d_in[18];
    const int* hop_length = (const int*)d_in[19];

    float* ws = (float*)d_ws;
    size_t cap = ws_size / sizeof(float);
    const size_t MH = (size_t)NO_HOPS * (MAX_HOP_LEN + 1) * D_MODEL;

    const size_t N_INW  = (size_t)NLAY * SZ_INW;
    const size_t N_OUTW = (size_t)NLAY * SZ_OUTW;
    const size_t N_F1W  = (size_t)NLAY * SZ_F1W;
    const size_t N_F2W  = (size_t)NLAY * SZ_F2W;
    const size_t WBF = (N_INW + N_OUTW + N_F1W + N_F2W) / 2;
    const size_t SK_ACC = (size_t)NSPLIT * N_FINAL * HEADS * DH;
    const size_t SK_MS  = (size_t)NSPLIT * N_FINAL * HEADS * 2;
    const size_t SZC = (size_t)3 * N_MASKED * D_MODEL / 2;   // compact buf (floats)

    int NM = 3;
    {
        size_t fixed3 = 3 * MH / 2 + 3 * MH * 3 / 2 + 3 * MH / 2 + 3 * MH / 2
                      + (size_t)3 * NO_HOPS * D_MODEL + 3 * N_LEVELS * D_MODEL + 768 + 4096
                      + WBF + SK_ACC + SK_MS + 3 * SZC;
        size_t ffmin = (size_t)3 * 128 * DFF / 2;
        if (fixed3 + ffmin > cap) NM = 1;
    }

    size_t off = 0;
    auto take = [&](size_t n) { float* p = ws + off; off += (n + 7) & ~(size_t)7; return p; };
    size_t xsz = (size_t)NM * MH;
    unsigned short* Xb     = (unsigned short*)take(xsz / 2);
    unsigned short* QKV    = (unsigned short*)take(xsz * 3 / 2);
    unsigned short* O      = (unsigned short*)take(xsz / 2);
    unsigned short* Tb     = (unsigned short*)take(xsz / 2);
    float*          HOPTOK = take((size_t)3 * NO_HOPS * D_MODEL);
    float*          LEVTOK = take((size_t)3 * N_LEVELS * D_MODEL);
    float*          GTOK   = take((size_t)3 * D_MODEL);
    int*            INV    = (int*)take(2048);            // 3*512 inv + 48 counts
    int*            COUNTS = INV + 3 * (N_LEVELS * MAX_LEV_LEN);
    float*          SKACC  = take(SK_ACC);
    float*          SKMS   = take(SK_MS);
    unsigned short* XC1    = (unsigned short*)take(SZC);
    unsigned short* TC     = (unsigned short*)take(SZC);
    unsigned short* XC2    = (unsigned short*)take(SZC);
    unsigned short* WINW   = (unsigned short*)take(N_INW / 2);
    unsigned short* WOUTW  = (unsigned short*)take(N_OUTW / 2);
    unsigned short* WF1    = (unsigned short*)take(N_F1W / 2);
    unsigned short* WF2    = (unsigned short*)take(N_F2W / 2);
    unsigned short* FF     = (unsigned short*)(ws + off);
    size_t ff_ushorts = (cap > off) ? (cap - off) * 2 : 0;
    int ff_rows = (int)(ff_ushorts / ((size_t)NM * DFF));
    int max_rows = NO_HOPS * (MAX_HOP_LEN + 1);
    if (ff_rows > max_rows) ff_rows = max_rows;
    if (ff_rows > 2048) ff_rows &= ~127;
    if (ff_rows < 128) ff_rows = 128;

    {
        long n0 = (long)(N_INW / 8), n1 = (long)(N_OUTW / 8);
        long n2 = (long)(N_F1W / 8), n3 = (long)(N_F2W / 8);
        long ntot = n0 + n1 + n2 + n3;
        hipLaunchKernelGGL(cvt_w4, dim3((ntot + 255) / 256), dim3(256), 0, stream,
                           in_w, WINW, n0, out_w, WOUTW, n1, ff1_w, WF1, n2, ff2_w, WF2, n3);
    }

    WB W;
    W.inw = WINW; W.outw = WOUTW; W.f1w = WF1; W.f2w = WF2;
    W.in_b = in_b; W.out_b = out_b; W.ff1_b = ff1_b; W.ff2_b = ff2_b;
    W.ln1_w = ln1_w; W.ln1_b = ln1_b; W.ln2_w = ln2_w; W.ln2_b = ln2_b;

    for (int ms = 0; ms < 3; ms += NM) {
        const int nm = NM;
        {
            int total = nm * NO_HOPS * (MAX_HOP_LEN + 1) * D_MODEL;
            hipLaunchKernelGGL(build_hop_seq_g, dim3((total + 255) / 256), dim3(256), 0, stream,
                               tokens + (size_t)(ms + 1) * N_NODES * D_MODEL,
                               hop_list + (size_t)ms * NO_HOPS * MAX_HOP_LEN,
                               hop_nodes, Xb, nm);
        }
        run_encoder_g(Xb, QKV, O, Tb, FF, XC1, TC, XC2, SKACC, SKMS, ff_rows,
                      nm, nm * NO_HOPS, MAX_HOP_LEN + 1,
                      hop_length + (size_t)ms * NO_HOPS, W, 1 + ms,
                      HOPTOK + (size_t)ms * NO_HOPS * D_MODEL, stream);

        hipLaunchKernelGGL(compute_pos_g, dim3(nm), dim3(NO_HOPS), 0, stream,
                           hop_lev + (size_t)ms * NO_HOPS, INV, COUNTS);
        {
            int total = nm * N_LEVELS * (MAX_LEV_LEN + 1) * D_MODEL;
            hipLaunchKernelGGL(build_level_seq_g, dim3((total + 255) / 256), dim3(256), 0, stream,
                               level_nodes, HOPTOK + (size_t)ms * NO_HOPS * D_MODEL,
                               INV, COUNTS, Xb, nm);
        }
        run_encoder_g(Xb, QKV, O, Tb, FF, XC1, TC, XC2, SKACC, SKMS, ff_rows,
                      nm, nm * N_LEVELS, MAX_LEV_LEN + 1,
                      COUNTS, W, 5 + ms,
                      LEVTOK + (size_t)ms * N_LEVELS * D_MODEL, stream);

        {
            int total = nm * (N_LEVELS + 1) * D_MODEL;
            hipLaunchKernelGGL(build_graph_seq_g, dim3((total + 255) / 256), dim3(256), 0, stream,
                               graph_nodes, LEVTOK + (size_t)ms * N_LEVELS * D_MODEL, Xb, nm);
        }
        run_encoder_g(Xb, QKV, O, Tb, FF, XC1, TC, XC2, SKACC, SKMS, ff_rows,
                      nm, nm, N_LEVELS + 1,
                      nullptr, W, 9 + ms,
                      GTOK + (size_t)ms * D_MODEL, stream);
    }

    {
        int total = N_FINAL * D_MODEL;
        hipLaunchKernelGGL(build_final_seq, dim3((total + 255) / 256), dim3(256), 0, stream,
                           masked_tokens, HOPTOK, LEVTOK, GTOK, Xb);
    }
    run_encoder_g(Xb, QKV, O, Tb, FF, XC1, TC, XC2, SKACC, SKMS, ff_rows,
                  1, 1, N_FINAL, nullptr, W, 12, (float*)d_out, stream);
}